// Round 6
// baseline (218.341 us; speedup 1.0000x reference)
//
#include <hip/hip_runtime.h>
#include <hip/hip_bf16.h>
#include <math.h>

// SAGAN attention block. Inputs/outputs fp32; internal matmuls bf16 MFMA.
// B=8, N=4096 (64x64 spatial), C=512, D=64.

typedef short v8s __attribute__((ext_vector_type(8)));
typedef unsigned short v4u __attribute__((ext_vector_type(4)));
typedef unsigned v4i __attribute__((ext_vector_type(4)));
typedef float v4f __attribute__((ext_vector_type(4)));

#define BB 8
#define NN 4096
#define CC 512
#define DD 64

__device__ __forceinline__ unsigned short f2bf(float f){
  union { float f; unsigned u; } v; v.f = f;
  unsigned r = (v.u + 0x7FFF + ((v.u >> 16) & 1)) >> 16;
  return (unsigned short)r;
}

// packed f32x2 -> bf16x2 (low = first arg)
#if __has_builtin(__builtin_amdgcn_cvt_pk_bf16_f32)
typedef __bf16 bf2_t __attribute__((ext_vector_type(2)));
__device__ __forceinline__ unsigned pkbf(float a, float b){
  bf2_t r = __builtin_amdgcn_cvt_pk_bf16_f32(a, b);
  union { bf2_t v; unsigned u; } c; c.v = r; return c.u;
}
#else
__device__ __forceinline__ unsigned pkbf(float a, float b){
  return (unsigned)f2bf(a) | ((unsigned)f2bf(b) << 16);
}
#endif

// raw v_exp_f32: skips OCML denormal-guard (cmp+cndmask+scale). Inputs below
// -126 flush to 0, which is exactly what softmax wants.
#if __has_builtin(__builtin_amdgcn_exp2f)
__device__ __forceinline__ float ex2(float x){ return __builtin_amdgcn_exp2f(x); }
#else
__device__ __forceinline__ float ex2(float x){ return exp2f(x); }
#endif

// async global->LDS, 16B per lane; LDS dest = wave-uniform base + lane*16
__device__ __forceinline__ void gload_lds16(const void* g, void* l){
  __builtin_amdgcn_global_load_lds(
      (const __attribute__((address_space(1))) void*)g,
      (__attribute__((address_space(3))) void*)l, 16, 0, 0);
}

// ---------------------------------------------------------------------------
// Kernel 0: convert fp32 weights to bf16, transposed (K-contiguous B-frags).
// ---------------------------------------------------------------------------
__global__ void transpose_w(const float* __restrict__ Wf,
                            const float* __restrict__ Wg,
                            const float* __restrict__ Wh,
                            const float* __restrict__ Wv,
                            unsigned short* __restrict__ Wt,
                            unsigned short* __restrict__ Wvt){
  int idx = blockIdx.x * 256 + threadIdx.x;
  if (idx < 3 * DD * CC){
    int p = idx / (DD * CC); int rem = idx % (DD * CC);
    int d = rem / CC; int c = rem % CC;
    const float* W = (p == 0) ? Wf : ((p == 1) ? Wg : Wh);
    Wt[idx] = f2bf(W[c * DD + d]);
  } else {
    int idx2 = idx - 3 * DD * CC;
    if (idx2 < CC * DD){
      int c = idx2 / DD; int d = idx2 % DD;
      Wvt[idx2] = f2bf(Wv[d * CC + c]);
    }
  }
}

// ---------------------------------------------------------------------------
// Kernel 1: fused projection GEMM.  f|g|h = x @ [Wf|Wg|Wh] + bias.
// f (query) pre-scaled by log2(e).  x converted fp32->bf16 with packed cvt.
// h written transposed (ht[b][d][n]) through an LDS transpose epilogue.
// Round 6: 8-wave blocks (512 thr).  Wave w owns row-group (w>>1)*16 and
// column-half (w&1): per-wave MFMA chain halves (12 vs 24) and waves/SIMD
// doubles 2->4, attacking the latency-bound regime (proj had 2 waves/SIMD
// and a serial chain with nothing co-resident to overlap).  Double-buffered
// LDS (one barrier per k-tile) retained.  LDS 72 KiB -> 2 blocks/CU.
// ---------------------------------------------------------------------------
__global__ __launch_bounds__(512) void proj_kernel(
    const float* __restrict__ x,             // [32768][512] fp32
    const unsigned short* __restrict__ Wt,   // [192][512] bf16
    const float* __restrict__ bf_,
    const float* __restrict__ bg_,
    const float* __restrict__ bh_,
    unsigned short* __restrict__ f,
    unsigned short* __restrict__ g,
    unsigned short* __restrict__ ht)
{
  __shared__ __align__(16) short lA[2][64][72];
  __shared__ __align__(16) short lB[2][192][72];
  int t = threadIdx.x;                   // 0..511
  int w = t >> 6, lane = t & 63;
  int quad = lane >> 4, l16 = lane & 15;
  int rowbase = blockIdx.x * 64;
  int m0 = (w >> 1) * 16;                // row-group
  int ch = w & 1;                        // column half (6 col-blocks each)

  v4f acc[6];
  #pragma unroll
  for (int i = 0; i < 6; i++) acc[i] = (v4f){0.f, 0.f, 0.f, 0.f};

  // A staging: 512 threads x 8 floats (32B coalesced per thread)
  int arow = t >> 3, aq8 = t & 7;
  const float* xrow = x + (rowbase + arow) * 512 + aq8 * 8;

  v4f a0, a1;                            // prefetch registers (x)
  v8s br[3];                             // prefetch registers (Wt)

  auto load_regs = [&](int kt){
    const float* xp = xrow + kt * 64;
    a0 = *(const v4f*)(xp);
    a1 = *(const v4f*)(xp + 4);
    #pragma unroll
    for (int r = 0; r < 3; r++){
      int chunk = t + r * 512;           // 1536 chunks = 192 rows x 8
      int row = chunk >> 3, c8 = chunk & 7;
      br[r] = *(const v8s*)(Wt + row * 512 + kt * 64 + c8 * 8);
    }
  };
  auto write_lds = [&](int buf){
    v4i c0 = { pkbf(a0[0],a0[1]), pkbf(a0[2],a0[3]),
               pkbf(a1[0],a1[1]), pkbf(a1[2],a1[3]) };
    *(v4i*)&lA[buf][arow][aq8 * 8] = c0;
    #pragma unroll
    for (int r = 0; r < 3; r++){
      int chunk = t + r * 512;
      int row = chunk >> 3, c8 = chunk & 7;
      *(v8s*)&lB[buf][row][c8 * 8] = br[r];
    }
  };

  load_regs(0);
  write_lds(0);
  __syncthreads();
  for (int kt = 0; kt < 8; ++kt){
    int cur = kt & 1;
    if (kt < 7) load_regs(kt + 1);       // issue next tile's global loads
    v8s A0 = *(const v8s*)&lA[cur][m0 + l16][quad * 8];
    v8s A1 = *(const v8s*)&lA[cur][m0 + l16][quad * 8 + 32];
    #pragma unroll
    for (int cb = 0; cb < 6; ++cb){
      int cbg = ch * 6 + cb;
      v8s b0 = *(const v8s*)&lB[cur][cbg * 16 + l16][quad * 8];
      v8s b1 = *(const v8s*)&lB[cur][cbg * 16 + l16][quad * 8 + 32];
      acc[cb] = __builtin_amdgcn_mfma_f32_16x16x32_bf16(A0, b0, acc[cb], 0, 0, 0);
      acc[cb] = __builtin_amdgcn_mfma_f32_16x16x32_bf16(A1, b1, acc[cb], 0, 0, 0);
    }
    if (kt < 7) write_lds(cur ^ 1);      // land prefetch in alternate buffer
    __syncthreads();                     // one barrier per k-tile
  }

  // f and g: direct stores (cols 0..127; ch=0 covers 0..95, ch=1 96..127)
  #pragma unroll
  for (int cb = 0; cb < 6; ++cb){
    int cbg = ch * 6 + cb;
    if (cbg < 8){
      int col = cbg * 16 + l16;
      int p = col >> 6, d = col & 63;
      float bb = (p == 0) ? bf_[d] : bg_[d];
      #pragma unroll
      for (int r = 0; r < 4; r++){
        int gr = rowbase + m0 + quad * 4 + r;
        float val = acc[cb][r] + bb;
        if (p == 0) f[gr * 64 + d] = f2bf(val * 1.44269504f);  // log2(e) fold
        else        g[gr * 64 + d] = f2bf(val);
      }
    }
  }

  // h (cols 128..191, all in ch=1 waves, cb 2..5): LDS transpose -> ht
  short (*lT)[65] = (short(*)[65])lB;
  if (ch == 1){
    #pragma unroll
    for (int cb = 2; cb < 6; ++cb){
      int d = (cb - 2) * 16 + l16;
      float bb = bh_[d];
      #pragma unroll
      for (int r = 0; r < 4; r++)
        lT[m0 + quad * 4 + r][d] = (short)f2bf(acc[cb][r] + bb);
    }
  }
  __syncthreads();
  {
    int dd = t >> 3, nseg = t & 7;       // 64 d x 8 row-segments of 8
    v8s h0;
    #pragma unroll
    for (int i = 0; i < 8; i++)
      h0[i] = lT[nseg * 8 + i][dd];
    int bidx = rowbase >> 12;
    int n0 = (rowbase & 4095) + nseg * 8;
    unsigned short* hp = ht + ((size_t)(bidx * 64 + dd)) * 4096 + n0;
    *(v8s*)hp = h0;
  }
}

// ---------------------------------------------------------------------------
// Kernel 2: flash attention, S^T form, no-max softmax (exp2 domain).
// Block = 128 Q rows (4 waves x 32, two 16-row groups per wave), niter
// key-tiles of 64 (must be EVEN).
// K/V tiles: double-buffered unpadded 64x64 in LDS, 16B-chunk XOR swizzle
// (c ^= row&7), staged via global_load_lds (swizzle folded into source addr).
// 2-phase pipeline: stage(next buf) -> compute(cur buf) -> one barrier/tile.
// Row-sums computed on the matrix pipe (all-ones B operand).
// lP chunk-major [wave][chunk8][16][8] = 2 KiB/wave, reused by both q-groups.
// ---------------------------------------------------------------------------
__global__ __launch_bounds__(256) void flash_kernel(
    const unsigned short* __restrict__ f,   // Q [B][N][64] (prescaled log2e)
    const unsigned short* __restrict__ g,   // K [B][N][64]
    const unsigned short* __restrict__ ht,  // V^T [B][64][N]
    float* __restrict__ Opart,              // [1024][128][64] fp32 (split)
    float* __restrict__ lipart,             // [1024][128]
    unsigned short* __restrict__ ctx,       // [B][N][64] (direct)
    int niter, int direct)
{
  __shared__ __align__(16) short lK[2][64 * 64];    // [buf][key][d] swizzled
  __shared__ __align__(16) short lV[2][64 * 64];    // [buf][d][key] swizzled
  __shared__ __align__(16) short lP[4][8][16][8];   // per-wave chunk-major P
  int t = threadIdx.x;
  int w = t >> 6, lane = t & 63;
  int quad = lane >> 4, l16 = lane & 15;
  int qt = blockIdx.x, sp = blockIdx.y, b = blockIdx.z;
  int q0 = qt * 128;
  int m0 = w * 32;                       // wave's q offset within block

  const unsigned short* fb = f  + b * NN * 64;
  const unsigned short* gb = g  + b * NN * 64;
  const unsigned short* hb = ht + b * 64 * NN;

  // Q as B-operand fragment (B[k=d][n=q]): lane n=l16=q, k=quad*8+j.
  // Two 16-row groups per wave.
  const unsigned short* qbase = fb + (q0 + m0 + l16) * 64;
  v8s QB00 = *(const v8s*)(qbase + quad * 8);
  v8s QB01 = *(const v8s*)(qbase + quad * 8 + 32);
  v8s QB10 = *(const v8s*)(qbase + 16 * 64 + quad * 8);
  v8s QB11 = *(const v8s*)(qbase + 16 * 64 + quad * 8 + 32);

  // staging: wave w fills LDS bytes [w*2048, w*2048+2048) in 2 calls of 1024B
  int j0 = sp * niter;
  const char* srcK[2]; const char* srcV[2];
  char* dstK[2][2]; char* dstV[2][2];
  #pragma unroll
  for (int k = 0; k < 2; k++){
    int row = w * 16 + k * 8 + (lane >> 3);
    int c = (lane & 7) ^ (row & 7);            // XOR swizzle on source
    srcK[k] = (const char*)gb + (size_t)j0 * 8192 + row * 128 + c * 16;
    srcV[k] = (const char*)hb + (size_t)row * 8192 + (size_t)j0 * 128 + c * 16;
    #pragma unroll
    for (int b2 = 0; b2 < 2; b2++){
      dstK[b2][k] = (char*)lK[b2] + w * 2048 + k * 1024;
      dstV[b2][k] = (char*)lV[b2] + w * 2048 + k * 1024;
    }
  }

  // loop-invariant LDS frag addresses per buffer (logical chunk ph / ph^4)
  int ph = quad ^ (l16 & 7);
  const short* kA0[2]; const short* kA1[2];
  const short* vB0[2]; const short* vB1[2];
  #pragma unroll
  for (int b2 = 0; b2 < 2; b2++){
    kA0[b2] = lK[b2] + l16 * 64 + ph * 8;
    kA1[b2] = lK[b2] + l16 * 64 + (ph ^ 4) * 8;
    vB0[b2] = lV[b2] + l16 * 64 + ph * 8;
    vB1[b2] = lV[b2] + l16 * 64 + (ph ^ 4) * 8;
  }

  v8s ones;                                   // bf16 1.0 broadcast (B-frag)
  #pragma unroll
  for (int i = 0; i < 8; i++) ones[i] = (short)0x3F80;

  v4f rz[2];                                  // rowsum acc per group
  rz[0] = (v4f){0.f, 0.f, 0.f, 0.f};
  rz[1] = (v4f){0.f, 0.f, 0.f, 0.f};
  v4f O[2][4];
  #pragma unroll
  for (int gi = 0; gi < 2; gi++)
    #pragma unroll
    for (int cb = 0; cb < 4; cb++) O[gi][cb] = (v4f){0.f, 0.f, 0.f, 0.f};

  auto stage = [&](int b2){
    #pragma unroll
    for (int k = 0; k < 2; k++){
      gload_lds16(srcK[k], dstK[b2][k]);
      gload_lds16(srcV[k], dstV[b2][k]);
      srcK[k] += 8192; srcV[k] += 128;
    }
  };

  auto compute = [&](int b2){
    // S^T(64key x 32q) = K · Q^T : st[g][cb][r] = S[q][key=cb*16+quad*4+r]
    v4f st[2][4];
    __builtin_amdgcn_s_setprio(1);
    #pragma unroll
    for (int cb = 0; cb < 4; cb++){
      v8s a0 = *(const v8s*)(kA0[b2] + cb * 1024);
      v8s a1 = *(const v8s*)(kA1[b2] + cb * 1024);
      v4f z0 = (v4f){0.f, 0.f, 0.f, 0.f};
      z0 = __builtin_amdgcn_mfma_f32_16x16x32_bf16(a0, QB00, z0, 0, 0, 0);
      st[0][cb] = __builtin_amdgcn_mfma_f32_16x16x32_bf16(a1, QB01, z0, 0, 0, 0);
      v4f z1 = (v4f){0.f, 0.f, 0.f, 0.f};
      z1 = __builtin_amdgcn_mfma_f32_16x16x32_bf16(a0, QB10, z1, 0, 0, 0);
      st[1][cb] = __builtin_amdgcn_mfma_f32_16x16x32_bf16(a1, QB11, z1, 0, 0, 0);
    }
    __builtin_amdgcn_s_setprio(0);

    // p = 2^s (raw v_exp), pack pairs via perm (bf16 trunc), b64 store to lP.
    // Chunk-major dest: chunk c = cb*2+(quad>>1) holds keys 8c..8c+7 of row
    // q=l16; this lane's 4-key run lands at short offset (quad&1)*4.
    auto packwrite = [&](int gi){
      #pragma unroll
      for (int cb = 0; cb < 4; cb++){
        float p0 = ex2(st[gi][cb][0]);
        float p1 = ex2(st[gi][cb][1]);
        float p2 = ex2(st[gi][cb][2]);
        float p3 = ex2(st[gi][cb][3]);
        unsigned d0 = __builtin_amdgcn_perm(__float_as_uint(p1), __float_as_uint(p0), 0x07060302u);
        unsigned d1 = __builtin_amdgcn_perm(__float_as_uint(p3), __float_as_uint(p2), 0x07060302u);
        uint2 pk; pk.x = d0; pk.y = d1;
        *(uint2*)&lP[w][cb * 2 + (quad >> 1)][l16][(quad & 1) * 4] = pk;
      }
    };

    // ---- group 0 through the shared 2 KiB lP buffer ----
    packwrite(0);
    // P A-frags: row=l16=q, k=quad*8+j -> chunk quad (PA*0) / quad+4 (PA*1)
    v8s PA00 = *(const v8s*)&lP[w][quad][l16][0];
    v8s PA01 = *(const v8s*)&lP[w][quad + 4][l16][0];
    // ---- group 1 reuses the buffer; same-wave DS order keeps it safe ----
    packwrite(1);

    __builtin_amdgcn_s_setprio(1);
    rz[0] = __builtin_amdgcn_mfma_f32_16x16x32_bf16(PA00, ones, rz[0], 0, 0, 0);
    rz[0] = __builtin_amdgcn_mfma_f32_16x16x32_bf16(PA01, ones, rz[0], 0, 0, 0);
    #pragma unroll
    for (int cb = 0; cb < 4; cb++){
      v8s vb0 = *(const v8s*)(vB0[b2] + cb * 1024);
      v8s vb1 = *(const v8s*)(vB1[b2] + cb * 1024);
      O[0][cb] = __builtin_amdgcn_mfma_f32_16x16x32_bf16(PA00, vb0, O[0][cb], 0, 0, 0);
      O[0][cb] = __builtin_amdgcn_mfma_f32_16x16x32_bf16(PA01, vb1, O[0][cb], 0, 0, 0);
    }
    __builtin_amdgcn_s_setprio(0);

    v8s PA10 = *(const v8s*)&lP[w][quad][l16][0];
    v8s PA11 = *(const v8s*)&lP[w][quad + 4][l16][0];

    __builtin_amdgcn_s_setprio(1);
    rz[1] = __builtin_amdgcn_mfma_f32_16x16x32_bf16(PA10, ones, rz[1], 0, 0, 0);
    rz[1] = __builtin_amdgcn_mfma_f32_16x16x32_bf16(PA11, ones, rz[1], 0, 0, 0);
    #pragma unroll
    for (int cb = 0; cb < 4; cb++){
      v8s vb0 = *(const v8s*)(vB0[b2] + cb * 1024);
      v8s vb1 = *(const v8s*)(vB1[b2] + cb * 1024);
      O[1][cb] = __builtin_amdgcn_mfma_f32_16x16x32_bf16(PA10, vb0, O[1][cb], 0, 0, 0);
      O[1][cb] = __builtin_amdgcn_mfma_f32_16x16x32_bf16(PA11, vb1, O[1][cb], 0, 0, 0);
    }
    __builtin_amdgcn_s_setprio(0);
  };

  // 2-phase pipeline, niter even: prologue fills buf0; loop unrolled by 2.
  stage(0);
  __syncthreads();                 // buf0 ready (syncthreads drains vmcnt)
  for (int jj = 0; jj < niter; jj += 2){
    stage(1);                      // prefetch tile jj+1 under compute of jj
    compute(0);
    __syncthreads();               // buf1 ready; buf0 reads done
    if (jj + 2 < niter) stage(0);  // prefetch tile jj+2
    compute(1);
    __syncthreads();               // buf0 ready; buf1 reads done
  }

  if (direct){
    #pragma unroll
    for (int gi = 0; gi < 2; gi++){
      float inv[4];
      #pragma unroll
      for (int r = 0; r < 4; r++)
        inv[r] = 1.0f / rz[gi][r];
      #pragma unroll
      for (int cb = 0; cb < 4; cb++)
        #pragma unroll
        for (int r = 0; r < 4; r++){
          int row = q0 + m0 + gi * 16 + quad * 4 + r;
          ctx[(b * NN + row) * 64 + cb * 16 + l16] = f2bf(O[gi][cb][r] * inv[r]);
        }
    }
  } else {
    int bf = (b * 32 + qt) * 4 + sp;
    if (l16 == 0){
      #pragma unroll
      for (int gi = 0; gi < 2; gi++)
        #pragma unroll
        for (int r = 0; r < 4; r++)
          lipart[bf * 128 + m0 + gi * 16 + quad * 4 + r] = rz[gi][r];
    }
    float* Ob = Opart + (size_t)bf * 8192;
    #pragma unroll
    for (int gi = 0; gi < 2; gi++)
      #pragma unroll
      for (int cb = 0; cb < 4; cb++)
        #pragma unroll
        for (int r = 0; r < 4; r++)
          Ob[(m0 + gi * 16 + quad * 4 + r) * 64 + cb * 16 + l16] = O[gi][cb][r];
  }
}

// ---------------------------------------------------------------------------
// Kernel 2b: combine split-K partials -> bf16 ctx.  float4 per thread.
// Opart groups are 128 rows per (b,qt): [256 groups][4 sp][128][64].
// ---------------------------------------------------------------------------
__global__ __launch_bounds__(256) void reduce_kernel(
    const float* __restrict__ Opart,
    const float* __restrict__ lipart,
    unsigned short* __restrict__ ctx)
{
  int i4 = blockIdx.x * 256 + threadIdx.x;      // 524288 total (x4 elements)
  int bqt = i4 >> 11;                           // (b*32+qt), 2048 vec4 each
  int rem = (i4 & 2047) << 2;                   // element offset within 8192
  int rl  = rem >> 6;                           // row within 128
  const float* Ob  = Opart  + (size_t)bqt * 4 * 8192;
  const float* lib = lipart + bqt * 4 * 128;
  v4f s = *(const v4f*)(Ob + rem);
  s = s + *(const v4f*)(Ob + 8192  + rem);
  s = s + *(const v4f*)(Ob + 16384 + rem);
  s = s + *(const v4f*)(Ob + 24576 + rem);
  float li = (lib[rl] + lib[128 + rl]) + (lib[256 + rl] + lib[384 + rl]);
  float inv = 1.0f / li;
  uint2 o; o.x = pkbf(s[0] * inv, s[1] * inv); o.y = pkbf(s[2] * inv, s[3] * inv);
  *(uint2*)(ctx + (size_t)bqt * 8192 + rem) = o;
}

// ---------------------------------------------------------------------------
// Kernel 3: out = gamma * ctx @ Wv + bv + x.  M=32768, K=64, N=512.
// ---------------------------------------------------------------------------
__global__ __launch_bounds__(256) void outproj_kernel(
    const unsigned short* __restrict__ ctx,
    const unsigned short* __restrict__ Wvt,  // [512][64] bf16
    const float* __restrict__ bv,
    const float* __restrict__ x,
    const float* __restrict__ gamma_p,
    float* __restrict__ out)
{
  __shared__ __align__(16) short lA[64][72];
  __shared__ __align__(16) short lB[128][72];
  int t = threadIdx.x;
  int w = t >> 6, lane = t & 63;
  int quad = lane >> 4, l16 = lane & 15;
  int rowbase = blockIdx.x * 64;
  int colbase = blockIdx.y * 128;
  float gamma = *gamma_p;

  #pragma unroll
  for (int r = 0; r < 2; r++){
    int chunk = t + r * 256;
    int row = chunk >> 3, c8 = chunk & 7;
    *(v8s*)&lA[row][c8 * 8] = *(const v8s*)(ctx + (rowbase + row) * 64 + c8 * 8);
  }
  #pragma unroll
  for (int r = 0; r < 4; r++){
    int chunk = t + r * 256;
    int row = chunk >> 3, c8 = chunk & 7;
    *(v8s*)&lB[row][c8 * 8] = *(const v8s*)(Wvt + (colbase + row) * 64 + c8 * 8);
  }
  __syncthreads();
  int m0 = w * 16;
  v8s A0 = *(const v8s*)&lA[m0 + l16][quad * 8];
  v8s A1 = *(const v8s*)&lA[m0 + l16][quad * 8 + 32];
  v4f acc[8];
  #pragma unroll
  for (int cb = 0; cb < 8; cb++){
    v8s b0 = *(const v8s*)&lB[cb * 16 + l16][quad * 8];
    v8s b1 = *(const v8s*)&lB[cb * 16 + l16][quad * 8 + 32];
    v4f z = (v4f){0.f, 0.f, 0.f, 0.f};
    z = __builtin_amdgcn_mfma_f32_16x16x32_bf16(A0, b0, z, 0, 0, 0);
    acc[cb] = __builtin_amdgcn_mfma_f32_16x16x32_bf16(A1, b1, z, 0, 0, 0);
  }
  #pragma unroll
  for (int cb = 0; cb < 8; cb++){
    int col = colbase + cb * 16 + l16;
    float bvv = bv[col];
    #pragma unroll
    for (int r = 0; r < 4; r++){
      int gr = rowbase + m0 + quad * 4 + r;
      out[gr * 512 + col] = gamma * acc[cb][r] + bvv + x[gr * 512 + col];
    }
  }
}

// ---------------------------------------------------------------------------
extern "C" void kernel_launch(void* const* d_in, const int* in_sizes, int n_in,
                              void* d_out, int out_size, void* d_ws, size_t ws_size,
                              hipStream_t stream) {
  const float* x   = (const float*)d_in[0];
  const float* Wf  = (const float*)d_in[1];
  const float* bf_ = (const float*)d_in[2];
  const float* Wg  = (const float*)d_in[3];
  const float* bg  = (const float*)d_in[4];
  const float* Wh  = (const float*)d_in[5];
  const float* bh  = (const float*)d_in[6];
  const float* Wv  = (const float*)d_in[7];
  const float* bv  = (const float*)d_in[8];
  const float* gam = (const float*)d_in[9];
  float* out = (float*)d_out;

  // workspace map (bytes):
  //   Wt   @ 0         (196608)
  //   Wvt  @ 196608    (65536)
  //   f    @ 262144    (4194304)
  //   g    @ 4456448   (4194304)
  //   ht   @ 8650752   (4194304)
  //   ctx  @ 12845056  (4194304)
  //   Opart @ 17039360 (33554432)   split-K partials [1024][128][64] f32
  //   lipart@ 50593792 (524288)     [1024][128] f32; total 51118080 (~48.8 MiB)
  char* ws = (char*)d_ws;
  unsigned short* Wt  = (unsigned short*)(ws);
  unsigned short* Wvt = (unsigned short*)(ws + 196608);
  unsigned short* f   = (unsigned short*)(ws + 262144);
  unsigned short* g   = (unsigned short*)(ws + 4456448);
  unsigned short* ht  = (unsigned short*)(ws + 8650752);
  unsigned short* ctx = (unsigned short*)(ws + 12845056);
  float* Opart  = (float*)(ws + 17039360);
  float* lipart = (float*)(ws + 50593792);

  transpose_w<<<512, 256, 0, stream>>>(Wf, Wg, Wh, Wv, Wt, Wvt);
  proj_kernel<<<512, 512, 0, stream>>>(x, Wt, bf_, bg, bh, f, g, ht);

  bool split = (ws_size >= (size_t)51118080);
  if (split){
    flash_kernel<<<dim3(32, 4, 8), 256, 0, stream>>>(f, g, ht, Opart, lipart, ctx, 16, 0);
    reduce_kernel<<<2048, 256, 0, stream>>>(Opart, lipart, ctx);
  } else {
    flash_kernel<<<dim3(32, 1, 8), 256, 0, stream>>>(f, g, ht, nullptr, nullptr, ctx, 64, 1);
  }
  outproj_kernel<<<dim3(512, 4), 256, 0, stream>>>(ctx, Wvt, bv, x, gam, out);
}

// Round 7
// 214.933 us; speedup vs baseline: 1.0159x; 1.0159x over previous
//
#include <hip/hip_runtime.h>
#include <hip/hip_bf16.h>
#include <math.h>

// SAGAN attention block. Inputs/outputs fp32; internal matmuls bf16 MFMA.
// B=8, N=4096 (64x64 spatial), C=512, D=64.

typedef short v8s __attribute__((ext_vector_type(8)));
typedef unsigned short v4u __attribute__((ext_vector_type(4)));
typedef unsigned v4i __attribute__((ext_vector_type(4)));
typedef float v4f __attribute__((ext_vector_type(4)));

#define BB 8
#define NN 4096
#define CC 512
#define DD 64

__device__ __forceinline__ unsigned short f2bf(float f){
  union { float f; unsigned u; } v; v.f = f;
  unsigned r = (v.u + 0x7FFF + ((v.u >> 16) & 1)) >> 16;
  return (unsigned short)r;
}

// packed f32x2 -> bf16x2 (low = first arg)
#if __has_builtin(__builtin_amdgcn_cvt_pk_bf16_f32)
typedef __bf16 bf2_t __attribute__((ext_vector_type(2)));
__device__ __forceinline__ unsigned pkbf(float a, float b){
  bf2_t r = __builtin_amdgcn_cvt_pk_bf16_f32(a, b);
  union { bf2_t v; unsigned u; } c; c.v = r; return c.u;
}
#else
__device__ __forceinline__ unsigned pkbf(float a, float b){
  return (unsigned)f2bf(a) | ((unsigned)f2bf(b) << 16);
}
#endif

// raw v_exp_f32: skips OCML denormal-guard (cmp+cndmask+scale). Inputs below
// -126 flush to 0, which is exactly what softmax wants.
#if __has_builtin(__builtin_amdgcn_exp2f)
__device__ __forceinline__ float ex2(float x){ return __builtin_amdgcn_exp2f(x); }
#else
__device__ __forceinline__ float ex2(float x){ return exp2f(x); }
#endif

// async global->LDS, 16B per lane; LDS dest = wave-uniform base + lane*16
__device__ __forceinline__ void gload_lds16(const void* g, void* l){
  __builtin_amdgcn_global_load_lds(
      (const __attribute__((address_space(1))) void*)g,
      (__attribute__((address_space(3))) void*)l, 16, 0, 0);
}

// ---------------------------------------------------------------------------
// Kernel 0: convert fp32 weights to bf16, transposed (K-contiguous B-frags).
// ---------------------------------------------------------------------------
__global__ void transpose_w(const float* __restrict__ Wf,
                            const float* __restrict__ Wg,
                            const float* __restrict__ Wh,
                            const float* __restrict__ Wv,
                            unsigned short* __restrict__ Wt,
                            unsigned short* __restrict__ Wvt){
  int idx = blockIdx.x * 256 + threadIdx.x;
  if (idx < 3 * DD * CC){
    int p = idx / (DD * CC); int rem = idx % (DD * CC);
    int d = rem / CC; int c = rem % CC;
    const float* W = (p == 0) ? Wf : ((p == 1) ? Wg : Wh);
    Wt[idx] = f2bf(W[c * DD + d]);
  } else {
    int idx2 = idx - 3 * DD * CC;
    if (idx2 < CC * DD){
      int c = idx2 / DD; int d = idx2 % DD;
      Wvt[idx2] = f2bf(Wv[d * CC + c]);
    }
  }
}

// ---------------------------------------------------------------------------
// Kernel 1: fused projection GEMM.  f|g|h = x @ [Wf|Wg|Wh] + bias.
// f (query) pre-scaled by log2(e).  x converted fp32->bf16 with packed cvt.
// h written transposed (ht[b][d][n]) through an LDS transpose epilogue.
// 8-wave blocks (512 thr): wave w owns row-group (w>>1)*16, column-half w&1.
// Double-buffered LDS, one barrier per k-tile.
// ---------------------------------------------------------------------------
__global__ __launch_bounds__(512) void proj_kernel(
    const float* __restrict__ x,             // [32768][512] fp32
    const unsigned short* __restrict__ Wt,   // [192][512] bf16
    const float* __restrict__ bf_,
    const float* __restrict__ bg_,
    const float* __restrict__ bh_,
    unsigned short* __restrict__ f,
    unsigned short* __restrict__ g,
    unsigned short* __restrict__ ht)
{
  __shared__ __align__(16) short lA[2][64][72];
  __shared__ __align__(16) short lB[2][192][72];
  int t = threadIdx.x;                   // 0..511
  int w = t >> 6, lane = t & 63;
  int quad = lane >> 4, l16 = lane & 15;
  int rowbase = blockIdx.x * 64;
  int m0 = (w >> 1) * 16;                // row-group
  int ch = w & 1;                        // column half (6 col-blocks each)

  v4f acc[6];
  #pragma unroll
  for (int i = 0; i < 6; i++) acc[i] = (v4f){0.f, 0.f, 0.f, 0.f};

  // A staging: 512 threads x 8 floats (32B coalesced per thread)
  int arow = t >> 3, aq8 = t & 7;
  const float* xrow = x + (rowbase + arow) * 512 + aq8 * 8;

  v4f a0, a1;                            // prefetch registers (x)
  v8s br[3];                             // prefetch registers (Wt)

  auto load_regs = [&](int kt){
    const float* xp = xrow + kt * 64;
    a0 = *(const v4f*)(xp);
    a1 = *(const v4f*)(xp + 4);
    #pragma unroll
    for (int r = 0; r < 3; r++){
      int chunk = t + r * 512;           // 1536 chunks = 192 rows x 8
      int row = chunk >> 3, c8 = chunk & 7;
      br[r] = *(const v8s*)(Wt + row * 512 + kt * 64 + c8 * 8);
    }
  };
  auto write_lds = [&](int buf){
    v4i c0 = { pkbf(a0[0],a0[1]), pkbf(a0[2],a0[3]),
               pkbf(a1[0],a1[1]), pkbf(a1[2],a1[3]) };
    *(v4i*)&lA[buf][arow][aq8 * 8] = c0;
    #pragma unroll
    for (int r = 0; r < 3; r++){
      int chunk = t + r * 512;
      int row = chunk >> 3, c8 = chunk & 7;
      *(v8s*)&lB[buf][row][c8 * 8] = br[r];
    }
  };

  load_regs(0);
  write_lds(0);
  __syncthreads();
  for (int kt = 0; kt < 8; ++kt){
    int cur = kt & 1;
    if (kt < 7) load_regs(kt + 1);       // issue next tile's global loads
    v8s A0 = *(const v8s*)&lA[cur][m0 + l16][quad * 8];
    v8s A1 = *(const v8s*)&lA[cur][m0 + l16][quad * 8 + 32];
    #pragma unroll
    for (int cb = 0; cb < 6; ++cb){
      int cbg = ch * 6 + cb;
      v8s b0 = *(const v8s*)&lB[cur][cbg * 16 + l16][quad * 8];
      v8s b1 = *(const v8s*)&lB[cur][cbg * 16 + l16][quad * 8 + 32];
      acc[cb] = __builtin_amdgcn_mfma_f32_16x16x32_bf16(A0, b0, acc[cb], 0, 0, 0);
      acc[cb] = __builtin_amdgcn_mfma_f32_16x16x32_bf16(A1, b1, acc[cb], 0, 0, 0);
    }
    if (kt < 7) write_lds(cur ^ 1);      // land prefetch in alternate buffer
    __syncthreads();                     // one barrier per k-tile
  }

  // f and g: direct stores (cols 0..127; ch=0 covers 0..95, ch=1 96..127)
  #pragma unroll
  for (int cb = 0; cb < 6; ++cb){
    int cbg = ch * 6 + cb;
    if (cbg < 8){
      int col = cbg * 16 + l16;
      int p = col >> 6, d = col & 63;
      float bb = (p == 0) ? bf_[d] : bg_[d];
      #pragma unroll
      for (int r = 0; r < 4; r++){
        int gr = rowbase + m0 + quad * 4 + r;
        float val = acc[cb][r] + bb;
        if (p == 0) f[gr * 64 + d] = f2bf(val * 1.44269504f);  // log2(e) fold
        else        g[gr * 64 + d] = f2bf(val);
      }
    }
  }

  // h (cols 128..191, all in ch=1 waves, cb 2..5): LDS transpose -> ht
  short (*lT)[65] = (short(*)[65])lB;
  if (ch == 1){
    #pragma unroll
    for (int cb = 2; cb < 6; ++cb){
      int d = (cb - 2) * 16 + l16;
      float bb = bh_[d];
      #pragma unroll
      for (int r = 0; r < 4; r++)
        lT[m0 + quad * 4 + r][d] = (short)f2bf(acc[cb][r] + bb);
    }
  }
  __syncthreads();
  {
    int dd = t >> 3, nseg = t & 7;       // 64 d x 8 row-segments of 8
    v8s h0;
    #pragma unroll
    for (int i = 0; i < 8; i++)
      h0[i] = lT[nseg * 8 + i][dd];
    int bidx = rowbase >> 12;
    int n0 = (rowbase & 4095) + nseg * 8;
    unsigned short* hp = ht + ((size_t)(bidx * 64 + dd)) * 4096 + n0;
    *(v8s*)hp = h0;
  }
}

// ---------------------------------------------------------------------------
// Kernel 2: flash attention, S^T form, no-max softmax (exp2 domain).
// Block = 128 Q rows (4 waves x 32, two 16-row groups per wave), niter
// key-tiles of 64 (must be EVEN).
// K/V tiles: double-buffered unpadded 64x64 in LDS, 16B-chunk XOR swizzle
// (c ^= row&7), staged via global_load_lds (swizzle folded into source addr).
// 2-phase pipeline: stage(next buf) -> compute(cur buf) -> one barrier/tile.
// Row-sums computed on the matrix pipe (all-ones B operand).
// lP chunk-major [wave][chunk8][16][8] = 2 KiB/wave, reused by both q-groups.
// Round 7: V fragments hoisted into registers once per tile and reused by
// both q-groups (-8 ds_read_b128/iter/wave = -25% of DS traffic; the two PV
// loops previously re-read V because lP writes blocked compiler CSE).
// Loaded after packwrite(1) where st[] dies, so peak VGPR is unchanged.
// ---------------------------------------------------------------------------
__global__ __launch_bounds__(256) void flash_kernel(
    const unsigned short* __restrict__ f,   // Q [B][N][64] (prescaled log2e)
    const unsigned short* __restrict__ g,   // K [B][N][64]
    const unsigned short* __restrict__ ht,  // V^T [B][64][N]
    float* __restrict__ Opart,              // [1024][128][64] fp32 (split)
    float* __restrict__ lipart,             // [1024][128]
    unsigned short* __restrict__ ctx,       // [B][N][64] (direct)
    int niter, int direct)
{
  __shared__ __align__(16) short lK[2][64 * 64];    // [buf][key][d] swizzled
  __shared__ __align__(16) short lV[2][64 * 64];    // [buf][d][key] swizzled
  __shared__ __align__(16) short lP[4][8][16][8];   // per-wave chunk-major P
  int t = threadIdx.x;
  int w = t >> 6, lane = t & 63;
  int quad = lane >> 4, l16 = lane & 15;
  int qt = blockIdx.x, sp = blockIdx.y, b = blockIdx.z;
  int q0 = qt * 128;
  int m0 = w * 32;                       // wave's q offset within block

  const unsigned short* fb = f  + b * NN * 64;
  const unsigned short* gb = g  + b * NN * 64;
  const unsigned short* hb = ht + b * 64 * NN;

  // Q as B-operand fragment (B[k=d][n=q]): lane n=l16=q, k=quad*8+j.
  // Two 16-row groups per wave.
  const unsigned short* qbase = fb + (q0 + m0 + l16) * 64;
  v8s QB00 = *(const v8s*)(qbase + quad * 8);
  v8s QB01 = *(const v8s*)(qbase + quad * 8 + 32);
  v8s QB10 = *(const v8s*)(qbase + 16 * 64 + quad * 8);
  v8s QB11 = *(const v8s*)(qbase + 16 * 64 + quad * 8 + 32);

  // staging: wave w fills LDS bytes [w*2048, w*2048+2048) in 2 calls of 1024B
  int j0 = sp * niter;
  const char* srcK[2]; const char* srcV[2];
  char* dstK[2][2]; char* dstV[2][2];
  #pragma unroll
  for (int k = 0; k < 2; k++){
    int row = w * 16 + k * 8 + (lane >> 3);
    int c = (lane & 7) ^ (row & 7);            // XOR swizzle on source
    srcK[k] = (const char*)gb + (size_t)j0 * 8192 + row * 128 + c * 16;
    srcV[k] = (const char*)hb + (size_t)row * 8192 + (size_t)j0 * 128 + c * 16;
    #pragma unroll
    for (int b2 = 0; b2 < 2; b2++){
      dstK[b2][k] = (char*)lK[b2] + w * 2048 + k * 1024;
      dstV[b2][k] = (char*)lV[b2] + w * 2048 + k * 1024;
    }
  }

  // loop-invariant LDS frag addresses per buffer (logical chunk ph / ph^4)
  int ph = quad ^ (l16 & 7);
  const short* kA0[2]; const short* kA1[2];
  const short* vB0[2]; const short* vB1[2];
  #pragma unroll
  for (int b2 = 0; b2 < 2; b2++){
    kA0[b2] = lK[b2] + l16 * 64 + ph * 8;
    kA1[b2] = lK[b2] + l16 * 64 + (ph ^ 4) * 8;
    vB0[b2] = lV[b2] + l16 * 64 + ph * 8;
    vB1[b2] = lV[b2] + l16 * 64 + (ph ^ 4) * 8;
  }

  v8s ones;                                   // bf16 1.0 broadcast (B-frag)
  #pragma unroll
  for (int i = 0; i < 8; i++) ones[i] = (short)0x3F80;

  v4f rz[2];                                  // rowsum acc per group
  rz[0] = (v4f){0.f, 0.f, 0.f, 0.f};
  rz[1] = (v4f){0.f, 0.f, 0.f, 0.f};
  v4f O[2][4];
  #pragma unroll
  for (int gi = 0; gi < 2; gi++)
    #pragma unroll
    for (int cb = 0; cb < 4; cb++) O[gi][cb] = (v4f){0.f, 0.f, 0.f, 0.f};

  auto stage = [&](int b2){
    #pragma unroll
    for (int k = 0; k < 2; k++){
      gload_lds16(srcK[k], dstK[b2][k]);
      gload_lds16(srcV[k], dstV[b2][k]);
      srcK[k] += 8192; srcV[k] += 128;
    }
  };

  auto compute = [&](int b2){
    // S^T(64key x 32q) = K · Q^T : st[g][cb][r] = S[q][key=cb*16+quad*4+r]
    v4f st[2][4];
    __builtin_amdgcn_s_setprio(1);
    #pragma unroll
    for (int cb = 0; cb < 4; cb++){
      v8s a0 = *(const v8s*)(kA0[b2] + cb * 1024);
      v8s a1 = *(const v8s*)(kA1[b2] + cb * 1024);
      v4f z0 = (v4f){0.f, 0.f, 0.f, 0.f};
      z0 = __builtin_amdgcn_mfma_f32_16x16x32_bf16(a0, QB00, z0, 0, 0, 0);
      st[0][cb] = __builtin_amdgcn_mfma_f32_16x16x32_bf16(a1, QB01, z0, 0, 0, 0);
      v4f z1 = (v4f){0.f, 0.f, 0.f, 0.f};
      z1 = __builtin_amdgcn_mfma_f32_16x16x32_bf16(a0, QB10, z1, 0, 0, 0);
      st[1][cb] = __builtin_amdgcn_mfma_f32_16x16x32_bf16(a1, QB11, z1, 0, 0, 0);
    }
    __builtin_amdgcn_s_setprio(0);

    // p = 2^s (raw v_exp), pack pairs via perm (bf16 trunc), b64 store to lP.
    // Chunk-major dest: chunk c = cb*2+(quad>>1) holds keys 8c..8c+7 of row
    // q=l16; this lane's 4-key run lands at short offset (quad&1)*4.
    auto packwrite = [&](int gi){
      #pragma unroll
      for (int cb = 0; cb < 4; cb++){
        float p0 = ex2(st[gi][cb][0]);
        float p1 = ex2(st[gi][cb][1]);
        float p2 = ex2(st[gi][cb][2]);
        float p3 = ex2(st[gi][cb][3]);
        unsigned d0 = __builtin_amdgcn_perm(__float_as_uint(p1), __float_as_uint(p0), 0x07060302u);
        unsigned d1 = __builtin_amdgcn_perm(__float_as_uint(p3), __float_as_uint(p2), 0x07060302u);
        uint2 pk; pk.x = d0; pk.y = d1;
        *(uint2*)&lP[w][cb * 2 + (quad >> 1)][l16][(quad & 1) * 4] = pk;
      }
    };

    // ---- group 0 through the shared 2 KiB lP buffer ----
    packwrite(0);
    // P A-frags: row=l16=q, k=quad*8+j -> chunk quad (PA*0) / quad+4 (PA*1)
    v8s PA00 = *(const v8s*)&lP[w][quad][l16][0];
    v8s PA01 = *(const v8s*)&lP[w][quad + 4][l16][0];
    // ---- group 1 reuses the buffer; same-wave DS order keeps it safe ----
    packwrite(1);

    // V fragments: read ONCE, reused by both q-groups (st[] is dead here,
    // so vb[] lands in freed registers; peak pressure unchanged).
    v8s vb[4][2];
    #pragma unroll
    for (int cb = 0; cb < 4; cb++){
      vb[cb][0] = *(const v8s*)(vB0[b2] + cb * 1024);
      vb[cb][1] = *(const v8s*)(vB1[b2] + cb * 1024);
    }

    __builtin_amdgcn_s_setprio(1);
    rz[0] = __builtin_amdgcn_mfma_f32_16x16x32_bf16(PA00, ones, rz[0], 0, 0, 0);
    rz[0] = __builtin_amdgcn_mfma_f32_16x16x32_bf16(PA01, ones, rz[0], 0, 0, 0);
    #pragma unroll
    for (int cb = 0; cb < 4; cb++){
      O[0][cb] = __builtin_amdgcn_mfma_f32_16x16x32_bf16(PA00, vb[cb][0], O[0][cb], 0, 0, 0);
      O[0][cb] = __builtin_amdgcn_mfma_f32_16x16x32_bf16(PA01, vb[cb][1], O[0][cb], 0, 0, 0);
    }
    __builtin_amdgcn_s_setprio(0);

    v8s PA10 = *(const v8s*)&lP[w][quad][l16][0];
    v8s PA11 = *(const v8s*)&lP[w][quad + 4][l16][0];

    __builtin_amdgcn_s_setprio(1);
    rz[1] = __builtin_amdgcn_mfma_f32_16x16x32_bf16(PA10, ones, rz[1], 0, 0, 0);
    rz[1] = __builtin_amdgcn_mfma_f32_16x16x32_bf16(PA11, ones, rz[1], 0, 0, 0);
    #pragma unroll
    for (int cb = 0; cb < 4; cb++){
      O[1][cb] = __builtin_amdgcn_mfma_f32_16x16x32_bf16(PA10, vb[cb][0], O[1][cb], 0, 0, 0);
      O[1][cb] = __builtin_amdgcn_mfma_f32_16x16x32_bf16(PA11, vb[cb][1], O[1][cb], 0, 0, 0);
    }
    __builtin_amdgcn_s_setprio(0);
  };

  // 2-phase pipeline, niter even: prologue fills buf0; loop unrolled by 2.
  stage(0);
  __syncthreads();                 // buf0 ready (syncthreads drains vmcnt)
  for (int jj = 0; jj < niter; jj += 2){
    stage(1);                      // prefetch tile jj+1 under compute of jj
    compute(0);
    __syncthreads();               // buf1 ready; buf0 reads done
    if (jj + 2 < niter) stage(0);  // prefetch tile jj+2
    compute(1);
    __syncthreads();               // buf0 ready; buf1 reads done
  }

  if (direct){
    #pragma unroll
    for (int gi = 0; gi < 2; gi++){
      float inv[4];
      #pragma unroll
      for (int r = 0; r < 4; r++)
        inv[r] = 1.0f / rz[gi][r];
      #pragma unroll
      for (int cb = 0; cb < 4; cb++)
        #pragma unroll
        for (int r = 0; r < 4; r++){
          int row = q0 + m0 + gi * 16 + quad * 4 + r;
          ctx[(b * NN + row) * 64 + cb * 16 + l16] = f2bf(O[gi][cb][r] * inv[r]);
        }
    }
  } else {
    int bf = (b * 32 + qt) * 4 + sp;
    if (l16 == 0){
      #pragma unroll
      for (int gi = 0; gi < 2; gi++)
        #pragma unroll
        for (int r = 0; r < 4; r++)
          lipart[bf * 128 + m0 + gi * 16 + quad * 4 + r] = rz[gi][r];
    }
    float* Ob = Opart + (size_t)bf * 8192;
    #pragma unroll
    for (int gi = 0; gi < 2; gi++)
      #pragma unroll
      for (int cb = 0; cb < 4; cb++)
        #pragma unroll
        for (int r = 0; r < 4; r++)
          Ob[(m0 + gi * 16 + quad * 4 + r) * 64 + cb * 16 + l16] = O[gi][cb][r];
  }
}

// ---------------------------------------------------------------------------
// Kernel 2b: combine split-K partials -> bf16 ctx.  float4 per thread.
// Opart groups are 128 rows per (b,qt): [256 groups][4 sp][128][64].
// ---------------------------------------------------------------------------
__global__ __launch_bounds__(256) void reduce_kernel(
    const float* __restrict__ Opart,
    const float* __restrict__ lipart,
    unsigned short* __restrict__ ctx)
{
  int i4 = blockIdx.x * 256 + threadIdx.x;      // 524288 total (x4 elements)
  int bqt = i4 >> 11;                           // (b*32+qt), 2048 vec4 each
  int rem = (i4 & 2047) << 2;                   // element offset within 8192
  int rl  = rem >> 6;                           // row within 128
  const float* Ob  = Opart  + (size_t)bqt * 4 * 8192;
  const float* lib = lipart + bqt * 4 * 128;
  v4f s = *(const v4f*)(Ob + rem);
  s = s + *(const v4f*)(Ob + 8192  + rem);
  s = s + *(const v4f*)(Ob + 16384 + rem);
  s = s + *(const v4f*)(Ob + 24576 + rem);
  float li = (lib[rl] + lib[128 + rl]) + (lib[256 + rl] + lib[384 + rl]);
  float inv = 1.0f / li;
  uint2 o; o.x = pkbf(s[0] * inv, s[1] * inv); o.y = pkbf(s[2] * inv, s[3] * inv);
  *(uint2*)(ctx + (size_t)bqt * 8192 + rem) = o;
}

// ---------------------------------------------------------------------------
// Kernel 3: out = gamma * ctx @ Wv + bv + x.  M=32768, K=64, N=512.
// ---------------------------------------------------------------------------
__global__ __launch_bounds__(256) void outproj_kernel(
    const unsigned short* __restrict__ ctx,
    const unsigned short* __restrict__ Wvt,  // [512][64] bf16
    const float* __restrict__ bv,
    const float* __restrict__ x,
    const float* __restrict__ gamma_p,
    float* __restrict__ out)
{
  __shared__ __align__(16) short lA[64][72];
  __shared__ __align__(16) short lB[128][72];
  int t = threadIdx.x;
  int w = t >> 6, lane = t & 63;
  int quad = lane >> 4, l16 = lane & 15;
  int rowbase = blockIdx.x * 64;
  int colbase = blockIdx.y * 128;
  float gamma = *gamma_p;

  #pragma unroll
  for (int r = 0; r < 2; r++){
    int chunk = t + r * 256;
    int row = chunk >> 3, c8 = chunk & 7;
    *(v8s*)&lA[row][c8 * 8] = *(const v8s*)(ctx + (rowbase + row) * 64 + c8 * 8);
  }
  #pragma unroll
  for (int r = 0; r < 4; r++){
    int chunk = t + r * 256;
    int row = chunk >> 3, c8 = chunk & 7;
    *(v8s*)&lB[row][c8 * 8] = *(const v8s*)(Wvt + (colbase + row) * 64 + c8 * 8);
  }
  __syncthreads();
  int m0 = w * 16;
  v8s A0 = *(const v8s*)&lA[m0 + l16][quad * 8];
  v8s A1 = *(const v8s*)&lA[m0 + l16][quad * 8 + 32];
  v4f acc[8];
  #pragma unroll
  for (int cb = 0; cb < 8; cb++){
    v8s b0 = *(const v8s*)&lB[cb * 16 + l16][quad * 8];
    v8s b1 = *(const v8s*)&lB[cb * 16 + l16][quad * 8 + 32];
    v4f z = (v4f){0.f, 0.f, 0.f, 0.f};
    z = __builtin_amdgcn_mfma_f32_16x16x32_bf16(A0, b0, z, 0, 0, 0);
    acc[cb] = __builtin_amdgcn_mfma_f32_16x16x32_bf16(A1, b1, z, 0, 0, 0);
  }
  #pragma unroll
  for (int cb = 0; cb < 8; cb++){
    int col = colbase + cb * 16 + l16;
    float bvv = bv[col];
    #pragma unroll
    for (int r = 0; r < 4; r++){
      int gr = rowbase + m0 + quad * 4 + r;
      out[gr * 512 + col] = gamma * acc[cb][r] + bvv + x[gr * 512 + col];
    }
  }
}

// ---------------------------------------------------------------------------
extern "C" void kernel_launch(void* const* d_in, const int* in_sizes, int n_in,
                              void* d_out, int out_size, void* d_ws, size_t ws_size,
                              hipStream_t stream) {
  const float* x   = (const float*)d_in[0];
  const float* Wf  = (const float*)d_in[1];
  const float* bf_ = (const float*)d_in[2];
  const float* Wg  = (const float*)d_in[3];
  const float* bg  = (const float*)d_in[4];
  const float* Wh  = (const float*)d_in[5];
  const float* bh  = (const float*)d_in[6];
  const float* Wv  = (const float*)d_in[7];
  const float* bv  = (const float*)d_in[8];
  const float* gam = (const float*)d_in[9];
  float* out = (float*)d_out;

  // workspace map (bytes):
  //   Wt   @ 0         (196608)
  //   Wvt  @ 196608    (65536)
  //   f    @ 262144    (4194304)
  //   g    @ 4456448   (4194304)
  //   ht   @ 8650752   (4194304)
  //   ctx  @ 12845056  (4194304)
  //   Opart @ 17039360 (33554432)   split-K partials [1024][128][64] f32
  //   lipart@ 50593792 (524288)     [1024][128] f32; total 51118080 (~48.8 MiB)
  char* ws = (char*)d_ws;
  unsigned short* Wt  = (unsigned short*)(ws);
  unsigned short* Wvt = (unsigned short*)(ws + 196608);
  unsigned short* f   = (unsigned short*)(ws + 262144);
  unsigned short* g   = (unsigned short*)(ws + 4456448);
  unsigned short* ht  = (unsigned short*)(ws + 8650752);
  unsigned short* ctx = (unsigned short*)(ws + 12845056);
  float* Opart  = (float*)(ws + 17039360);
  float* lipart = (float*)(ws + 50593792);

  transpose_w<<<512, 256, 0, stream>>>(Wf, Wg, Wh, Wv, Wt, Wvt);
  proj_kernel<<<512, 512, 0, stream>>>(x, Wt, bf_, bg, bh, f, g, ht);

  bool split = (ws_size >= (size_t)51118080);
  if (split){
    flash_kernel<<<dim3(32, 4, 8), 256, 0, stream>>>(f, g, ht, Opart, lipart, ctx, 16, 0);
    reduce_kernel<<<2048, 256, 0, stream>>>(Opart, lipart, ctx);
  } else {
    flash_kernel<<<dim3(32, 1, 8), 256, 0, stream>>>(f, g, ht, nullptr, nullptr, ctx, 64, 1);
  }
  outproj_kernel<<<dim3(512, 4), 256, 0, stream>>>(ctx, Wvt, bv, x, gam, out);
}

// Round 9
// 202.722 us; speedup vs baseline: 1.0770x; 1.0602x over previous
//
#include <hip/hip_runtime.h>
#include <hip/hip_bf16.h>
#include <math.h>

// SAGAN attention block. Inputs/outputs fp32; internal matmuls bf16 MFMA.
// B=8, N=4096 (64x64 spatial), C=512, D=64.

typedef short v8s __attribute__((ext_vector_type(8)));
typedef unsigned short v4u __attribute__((ext_vector_type(4)));
typedef unsigned v4i __attribute__((ext_vector_type(4)));
typedef float v4f __attribute__((ext_vector_type(4)));

#define BB 8
#define NN 4096
#define CC 512
#define DD 64

__device__ __forceinline__ unsigned short f2bf(float f){
  union { float f; unsigned u; } v; v.f = f;
  unsigned r = (v.u + 0x7FFF + ((v.u >> 16) & 1)) >> 16;
  return (unsigned short)r;
}

// packed f32x2 -> bf16x2 (low = first arg)
#if __has_builtin(__builtin_amdgcn_cvt_pk_bf16_f32)
typedef __bf16 bf2_t __attribute__((ext_vector_type(2)));
__device__ __forceinline__ unsigned pkbf(float a, float b){
  bf2_t r = __builtin_amdgcn_cvt_pk_bf16_f32(a, b);
  union { bf2_t v; unsigned u; } c; c.v = r; return c.u;
}
#else
__device__ __forceinline__ unsigned pkbf(float a, float b){
  return (unsigned)f2bf(a) | ((unsigned)f2bf(b) << 16);
}
#endif

// raw v_exp_f32: skips OCML denormal-guard (cmp+cndmask+scale). Inputs below
// -126 flush to 0, which is exactly what softmax wants.
#if __has_builtin(__builtin_amdgcn_exp2f)
__device__ __forceinline__ float ex2(float x){ return __builtin_amdgcn_exp2f(x); }
#else
__device__ __forceinline__ float ex2(float x){ return exp2f(x); }
#endif

// async global->LDS, 16B per lane; LDS dest = wave-uniform base + lane*16
__device__ __forceinline__ void gload_lds16(const void* g, void* l){
  __builtin_amdgcn_global_load_lds(
      (const __attribute__((address_space(1))) void*)g,
      (__attribute__((address_space(3))) void*)l, 16, 0, 0);
}

// ---------------------------------------------------------------------------
// Kernel 0: convert fp32 weights to bf16, transposed (K-contiguous B-frags).
// ---------------------------------------------------------------------------
__global__ void transpose_w(const float* __restrict__ Wf,
                            const float* __restrict__ Wg,
                            const float* __restrict__ Wh,
                            const float* __restrict__ Wv,
                            unsigned short* __restrict__ Wt,
                            unsigned short* __restrict__ Wvt){
  int idx = blockIdx.x * 256 + threadIdx.x;
  if (idx < 3 * DD * CC){
    int p = idx / (DD * CC); int rem = idx % (DD * CC);
    int d = rem / CC; int c = rem % CC;
    const float* W = (p == 0) ? Wf : ((p == 1) ? Wg : Wh);
    Wt[idx] = f2bf(W[c * DD + d]);
  } else {
    int idx2 = idx - 3 * DD * CC;
    if (idx2 < CC * DD){
      int c = idx2 / DD; int d = idx2 % DD;
      Wvt[idx2] = f2bf(Wv[d * CC + c]);
    }
  }
}

// ---------------------------------------------------------------------------
// Kernel 1: fused projection GEMM.  f|g|h = x @ [Wf|Wg|Wh] + bias.
// f (query) pre-scaled by log2(e).  x converted fp32->bf16 with packed cvt.
// h written transposed (ht[b][d][n]) through an LDS transpose epilogue.
// 8-wave blocks (512 thr): wave w owns row-group (w>>1)*16, column-half w&1.
// Double-buffered LDS, one barrier per k-tile.
// ---------------------------------------------------------------------------
__global__ __launch_bounds__(512) void proj_kernel(
    const float* __restrict__ x,             // [32768][512] fp32
    const unsigned short* __restrict__ Wt,   // [192][512] bf16
    const float* __restrict__ bf_,
    const float* __restrict__ bg_,
    const float* __restrict__ bh_,
    unsigned short* __restrict__ f,
    unsigned short* __restrict__ g,
    unsigned short* __restrict__ ht)
{
  __shared__ __align__(16) short lA[2][64][72];
  __shared__ __align__(16) short lB[2][192][72];
  int t = threadIdx.x;                   // 0..511
  int w = t >> 6, lane = t & 63;
  int quad = lane >> 4, l16 = lane & 15;
  int rowbase = blockIdx.x * 64;
  int m0 = (w >> 1) * 16;                // row-group
  int ch = w & 1;                        // column half (6 col-blocks each)

  v4f acc[6];
  #pragma unroll
  for (int i = 0; i < 6; i++) acc[i] = (v4f){0.f, 0.f, 0.f, 0.f};

  // A staging: 512 threads x 8 floats (32B coalesced per thread)
  int arow = t >> 3, aq8 = t & 7;
  const float* xrow = x + (rowbase + arow) * 512 + aq8 * 8;

  v4f a0, a1;                            // prefetch registers (x)
  v8s br[3];                             // prefetch registers (Wt)

  auto load_regs = [&](int kt){
    const float* xp = xrow + kt * 64;
    a0 = *(const v4f*)(xp);
    a1 = *(const v4f*)(xp + 4);
    #pragma unroll
    for (int r = 0; r < 3; r++){
      int chunk = t + r * 512;           // 1536 chunks = 192 rows x 8
      int row = chunk >> 3, c8 = chunk & 7;
      br[r] = *(const v8s*)(Wt + row * 512 + kt * 64 + c8 * 8);
    }
  };
  auto write_lds = [&](int buf){
    v4i c0 = { pkbf(a0[0],a0[1]), pkbf(a0[2],a0[3]),
               pkbf(a1[0],a1[1]), pkbf(a1[2],a1[3]) };
    *(v4i*)&lA[buf][arow][aq8 * 8] = c0;
    #pragma unroll
    for (int r = 0; r < 3; r++){
      int chunk = t + r * 512;
      int row = chunk >> 3, c8 = chunk & 7;
      *(v8s*)&lB[buf][row][c8 * 8] = br[r];
    }
  };

  load_regs(0);
  write_lds(0);
  __syncthreads();
  for (int kt = 0; kt < 8; ++kt){
    int cur = kt & 1;
    if (kt < 7) load_regs(kt + 1);       // issue next tile's global loads
    v8s A0 = *(const v8s*)&lA[cur][m0 + l16][quad * 8];
    v8s A1 = *(const v8s*)&lA[cur][m0 + l16][quad * 8 + 32];
    #pragma unroll
    for (int cb = 0; cb < 6; ++cb){
      int cbg = ch * 6 + cb;
      v8s b0 = *(const v8s*)&lB[cur][cbg * 16 + l16][quad * 8];
      v8s b1 = *(const v8s*)&lB[cur][cbg * 16 + l16][quad * 8 + 32];
      acc[cb] = __builtin_amdgcn_mfma_f32_16x16x32_bf16(A0, b0, acc[cb], 0, 0, 0);
      acc[cb] = __builtin_amdgcn_mfma_f32_16x16x32_bf16(A1, b1, acc[cb], 0, 0, 0);
    }
    if (kt < 7) write_lds(cur ^ 1);      // land prefetch in alternate buffer
    __syncthreads();                     // one barrier per k-tile
  }

  // f and g: direct stores (cols 0..127; ch=0 covers 0..95, ch=1 96..127)
  #pragma unroll
  for (int cb = 0; cb < 6; ++cb){
    int cbg = ch * 6 + cb;
    if (cbg < 8){
      int col = cbg * 16 + l16;
      int p = col >> 6, d = col & 63;
      float bb = (p == 0) ? bf_[d] : bg_[d];
      #pragma unroll
      for (int r = 0; r < 4; r++){
        int gr = rowbase + m0 + quad * 4 + r;
        float val = acc[cb][r] + bb;
        if (p == 0) f[gr * 64 + d] = f2bf(val * 1.44269504f);  // log2(e) fold
        else        g[gr * 64 + d] = f2bf(val);
      }
    }
  }

  // h (cols 128..191, all in ch=1 waves, cb 2..5): LDS transpose -> ht
  short (*lT)[65] = (short(*)[65])lB;
  if (ch == 1){
    #pragma unroll
    for (int cb = 2; cb < 6; ++cb){
      int d = (cb - 2) * 16 + l16;
      float bb = bh_[d];
      #pragma unroll
      for (int r = 0; r < 4; r++)
        lT[m0 + quad * 4 + r][d] = (short)f2bf(acc[cb][r] + bb);
    }
  }
  __syncthreads();
  {
    int dd = t >> 3, nseg = t & 7;       // 64 d x 8 row-segments of 8
    v8s h0;
    #pragma unroll
    for (int i = 0; i < 8; i++)
      h0[i] = lT[nseg * 8 + i][dd];
    int bidx = rowbase >> 12;
    int n0 = (rowbase & 4095) + nseg * 8;
    unsigned short* hp = ht + ((size_t)(bidx * 64 + dd)) * 4096 + n0;
    *(v8s*)hp = h0;
  }
}

// ---------------------------------------------------------------------------
// Kernel 2: flash attention, S^T form, no-max softmax (exp2 domain).
// Block = 128 Q rows (4 waves x 32, two 16-row groups per wave), niter
// key-tiles of 64 (must be EVEN).
// K/V tiles: double-buffered unpadded 64x64 in LDS, 16B-chunk XOR swizzle
// (c ^= row&7), staged via global_load_lds (swizzle folded into source addr).
// 2-phase pipeline: stage(next buf) -> compute(cur buf) -> one barrier/tile.
// Row-sums computed on the matrix pipe (all-ones B operand).
// lP chunk-major [wave][chunk8][16][8] = 2 KiB/wave, reused by both q-groups.
// V fragments hoisted to registers once per tile, reused by both q-groups.
// ---------------------------------------------------------------------------
__global__ __launch_bounds__(256) void flash_kernel(
    const unsigned short* __restrict__ f,   // Q [B][N][64] (prescaled log2e)
    const unsigned short* __restrict__ g,   // K [B][N][64]
    const unsigned short* __restrict__ ht,  // V^T [B][64][N]
    float* __restrict__ Opart,              // [1024][128][64] fp32 (split)
    float* __restrict__ lipart,             // [1024][128]
    unsigned short* __restrict__ ctx,       // [B][N][64] (direct)
    int niter, int direct)
{
  __shared__ __align__(16) short lK[2][64 * 64];    // [buf][key][d] swizzled
  __shared__ __align__(16) short lV[2][64 * 64];    // [buf][d][key] swizzled
  __shared__ __align__(16) short lP[4][8][16][8];   // per-wave chunk-major P
  int t = threadIdx.x;
  int w = t >> 6, lane = t & 63;
  int quad = lane >> 4, l16 = lane & 15;
  int qt = blockIdx.x, sp = blockIdx.y, b = blockIdx.z;
  int q0 = qt * 128;
  int m0 = w * 32;                       // wave's q offset within block

  const unsigned short* fb = f  + b * NN * 64;
  const unsigned short* gb = g  + b * NN * 64;
  const unsigned short* hb = ht + b * 64 * NN;

  // Q as B-operand fragment (B[k=d][n=q]): lane n=l16=q, k=quad*8+j.
  // Two 16-row groups per wave.
  const unsigned short* qbase = fb + (q0 + m0 + l16) * 64;
  v8s QB00 = *(const v8s*)(qbase + quad * 8);
  v8s QB01 = *(const v8s*)(qbase + quad * 8 + 32);
  v8s QB10 = *(const v8s*)(qbase + 16 * 64 + quad * 8);
  v8s QB11 = *(const v8s*)(qbase + 16 * 64 + quad * 8 + 32);

  // staging: wave w fills LDS bytes [w*2048, w*2048+2048) in 2 calls of 1024B
  int j0 = sp * niter;
  const char* srcK[2]; const char* srcV[2];
  char* dstK[2][2]; char* dstV[2][2];
  #pragma unroll
  for (int k = 0; k < 2; k++){
    int row = w * 16 + k * 8 + (lane >> 3);
    int c = (lane & 7) ^ (row & 7);            // XOR swizzle on source
    srcK[k] = (const char*)gb + (size_t)j0 * 8192 + row * 128 + c * 16;
    srcV[k] = (const char*)hb + (size_t)row * 8192 + (size_t)j0 * 128 + c * 16;
    #pragma unroll
    for (int b2 = 0; b2 < 2; b2++){
      dstK[b2][k] = (char*)lK[b2] + w * 2048 + k * 1024;
      dstV[b2][k] = (char*)lV[b2] + w * 2048 + k * 1024;
    }
  }

  // loop-invariant LDS frag addresses per buffer (logical chunk ph / ph^4)
  int ph = quad ^ (l16 & 7);
  const short* kA0[2]; const short* kA1[2];
  const short* vB0[2]; const short* vB1[2];
  #pragma unroll
  for (int b2 = 0; b2 < 2; b2++){
    kA0[b2] = lK[b2] + l16 * 64 + ph * 8;
    kA1[b2] = lK[b2] + l16 * 64 + (ph ^ 4) * 8;
    vB0[b2] = lV[b2] + l16 * 64 + ph * 8;
    vB1[b2] = lV[b2] + l16 * 64 + (ph ^ 4) * 8;
  }

  v8s ones;                                   // bf16 1.0 broadcast (B-frag)
  #pragma unroll
  for (int i = 0; i < 8; i++) ones[i] = (short)0x3F80;

  v4f rz[2];                                  // rowsum acc per group
  rz[0] = (v4f){0.f, 0.f, 0.f, 0.f};
  rz[1] = (v4f){0.f, 0.f, 0.f, 0.f};
  v4f O[2][4];
  #pragma unroll
  for (int gi = 0; gi < 2; gi++)
    #pragma unroll
    for (int cb = 0; cb < 4; cb++) O[gi][cb] = (v4f){0.f, 0.f, 0.f, 0.f};

  auto stage = [&](int b2){
    #pragma unroll
    for (int k = 0; k < 2; k++){
      gload_lds16(srcK[k], dstK[b2][k]);
      gload_lds16(srcV[k], dstV[b2][k]);
      srcK[k] += 8192; srcV[k] += 128;
    }
  };

  auto compute = [&](int b2){
    // S^T(64key x 32q) = K · Q^T : st[g][cb][r] = S[q][key=cb*16+quad*4+r]
    v4f st[2][4];
    __builtin_amdgcn_s_setprio(1);
    #pragma unroll
    for (int cb = 0; cb < 4; cb++){
      v8s a0 = *(const v8s*)(kA0[b2] + cb * 1024);
      v8s a1 = *(const v8s*)(kA1[b2] + cb * 1024);
      v4f z0 = (v4f){0.f, 0.f, 0.f, 0.f};
      z0 = __builtin_amdgcn_mfma_f32_16x16x32_bf16(a0, QB00, z0, 0, 0, 0);
      st[0][cb] = __builtin_amdgcn_mfma_f32_16x16x32_bf16(a1, QB01, z0, 0, 0, 0);
      v4f z1 = (v4f){0.f, 0.f, 0.f, 0.f};
      z1 = __builtin_amdgcn_mfma_f32_16x16x32_bf16(a0, QB10, z1, 0, 0, 0);
      st[1][cb] = __builtin_amdgcn_mfma_f32_16x16x32_bf16(a1, QB11, z1, 0, 0, 0);
    }
    __builtin_amdgcn_s_setprio(0);

    // p = 2^s (raw v_exp), pack pairs via perm (bf16 trunc), b64 store to lP.
    // Chunk-major dest: chunk c = cb*2+(quad>>1) holds keys 8c..8c+7 of row
    // q=l16; this lane's 4-key run lands at short offset (quad&1)*4.
    auto packwrite = [&](int gi){
      #pragma unroll
      for (int cb = 0; cb < 4; cb++){
        float p0 = ex2(st[gi][cb][0]);
        float p1 = ex2(st[gi][cb][1]);
        float p2 = ex2(st[gi][cb][2]);
        float p3 = ex2(st[gi][cb][3]);
        unsigned d0 = __builtin_amdgcn_perm(__float_as_uint(p1), __float_as_uint(p0), 0x07060302u);
        unsigned d1 = __builtin_amdgcn_perm(__float_as_uint(p3), __float_as_uint(p2), 0x07060302u);
        uint2 pk; pk.x = d0; pk.y = d1;
        *(uint2*)&lP[w][cb * 2 + (quad >> 1)][l16][(quad & 1) * 4] = pk;
      }
    };

    // ---- group 0 through the shared 2 KiB lP buffer ----
    packwrite(0);
    // P A-frags: row=l16=q, k=quad*8+j -> chunk quad (PA*0) / quad+4 (PA*1)
    v8s PA00 = *(const v8s*)&lP[w][quad][l16][0];
    v8s PA01 = *(const v8s*)&lP[w][quad + 4][l16][0];
    // ---- group 1 reuses the buffer; same-wave DS order keeps it safe ----
    packwrite(1);

    // V fragments: read ONCE, reused by both q-groups (st[] is dead here,
    // so vb[] lands in freed registers; peak pressure unchanged).
    v8s vb[4][2];
    #pragma unroll
    for (int cb = 0; cb < 4; cb++){
      vb[cb][0] = *(const v8s*)(vB0[b2] + cb * 1024);
      vb[cb][1] = *(const v8s*)(vB1[b2] + cb * 1024);
    }

    __builtin_amdgcn_s_setprio(1);
    rz[0] = __builtin_amdgcn_mfma_f32_16x16x32_bf16(PA00, ones, rz[0], 0, 0, 0);
    rz[0] = __builtin_amdgcn_mfma_f32_16x16x32_bf16(PA01, ones, rz[0], 0, 0, 0);
    #pragma unroll
    for (int cb = 0; cb < 4; cb++){
      O[0][cb] = __builtin_amdgcn_mfma_f32_16x16x32_bf16(PA00, vb[cb][0], O[0][cb], 0, 0, 0);
      O[0][cb] = __builtin_amdgcn_mfma_f32_16x16x32_bf16(PA01, vb[cb][1], O[0][cb], 0, 0, 0);
    }
    __builtin_amdgcn_s_setprio(0);

    v8s PA10 = *(const v8s*)&lP[w][quad][l16][0];
    v8s PA11 = *(const v8s*)&lP[w][quad + 4][l16][0];

    __builtin_amdgcn_s_setprio(1);
    rz[1] = __builtin_amdgcn_mfma_f32_16x16x32_bf16(PA10, ones, rz[1], 0, 0, 0);
    rz[1] = __builtin_amdgcn_mfma_f32_16x16x32_bf16(PA11, ones, rz[1], 0, 0, 0);
    #pragma unroll
    for (int cb = 0; cb < 4; cb++){
      O[1][cb] = __builtin_amdgcn_mfma_f32_16x16x32_bf16(PA10, vb[cb][0], O[1][cb], 0, 0, 0);
      O[1][cb] = __builtin_amdgcn_mfma_f32_16x16x32_bf16(PA11, vb[cb][1], O[1][cb], 0, 0, 0);
    }
    __builtin_amdgcn_s_setprio(0);
  };

  // 2-phase pipeline, niter even: prologue fills buf0; loop unrolled by 2.
  stage(0);
  __syncthreads();                 // buf0 ready (syncthreads drains vmcnt)
  for (int jj = 0; jj < niter; jj += 2){
    stage(1);                      // prefetch tile jj+1 under compute of jj
    compute(0);
    __syncthreads();               // buf1 ready; buf0 reads done
    if (jj + 2 < niter) stage(0);  // prefetch tile jj+2
    compute(1);
    __syncthreads();               // buf0 ready; buf1 reads done
  }

  if (direct){
    #pragma unroll
    for (int gi = 0; gi < 2; gi++){
      float inv[4];
      #pragma unroll
      for (int r = 0; r < 4; r++)
        inv[r] = 1.0f / rz[gi][r];
      #pragma unroll
      for (int cb = 0; cb < 4; cb++)
        #pragma unroll
        for (int r = 0; r < 4; r++){
          int row = q0 + m0 + gi * 16 + quad * 4 + r;
          ctx[(b * NN + row) * 64 + cb * 16 + l16] = f2bf(O[gi][cb][r] * inv[r]);
        }
    }
  } else {
    int bf = (b * 32 + qt) * 4 + sp;
    if (l16 == 0){
      #pragma unroll
      for (int gi = 0; gi < 2; gi++)
        #pragma unroll
        for (int r = 0; r < 4; r++)
          lipart[bf * 128 + m0 + gi * 16 + quad * 4 + r] = rz[gi][r];
    }
    float* Ob = Opart + (size_t)bf * 8192;
    #pragma unroll
    for (int gi = 0; gi < 2; gi++)
      #pragma unroll
      for (int cb = 0; cb < 4; cb++)
        #pragma unroll
        for (int r = 0; r < 4; r++)
          Ob[(m0 + gi * 16 + quad * 4 + r) * 64 + cb * 16 + l16] = O[gi][cb][r];
  }
}

// ---------------------------------------------------------------------------
// Kernel 3 (split path): FUSED reduce + outproj.
// out = gamma * (sum_sp Opart / li) @ Wv + bv + x.  512 blocks x 512 thr.
// Block = 64 rows x all 512 cols.  ctx never touches HBM:
//   stage A: normalize Opart/lipart in-register -> bf16 A-tile in LDS.
//   stage B: full Wvt (64 KB) with 16B-chunk XOR swizzle (conflict-free
//            B-frag reads from unpadded [512][64]).
// 8 waves: wave w -> row-group (w&3)*16, col-half w>>2 (16 col-blocks each).
// LDS = 9.2 + 64 KB = 73.2 KB -> 2 blocks/CU.
// ---------------------------------------------------------------------------
__global__ __launch_bounds__(512) void outfuse_kernel(
    const float* __restrict__ Opart,         // [256 grp][4 sp][128][64]
    const float* __restrict__ lipart,        // [256 grp][4 sp][128]
    const unsigned short* __restrict__ Wvt,  // [512][64] bf16
    const float* __restrict__ bv,
    const float* __restrict__ x,
    const float* __restrict__ gamma_p,
    float* __restrict__ out)
{
  __shared__ __align__(16) short lA[64][72];
  __shared__ __align__(16) short lB[512][64];   // XOR-swizzled 16B chunks
  int t = threadIdx.x;                   // 0..511
  int lane = t & 63;
  int w = t >> 6;
  int quad = lane >> 4, l16 = lane & 15;
  int rowbase = blockIdx.x * 64;
  float gamma = *gamma_p;

  // ---- stage A: ctx tile from split-K partials (no HBM round trip) ----
  {
    int rl = t >> 3, d8 = (t & 7) * 8;   // row-local 0..63, d offset 0..56
    int group = rowbase >> 7;            // Opart group = 128 global rows
    int inrow = (rowbase & 127) + rl;
    const float* Ob  = Opart  + (size_t)group * 32768 + inrow * 64 + d8;
    const float* lib = lipart + group * 512 + inrow;
    v4f s0 = *(const v4f*)(Ob);
    v4f s1 = *(const v4f*)(Ob + 4);
    float li = lib[0];
    #pragma unroll
    for (int sp = 1; sp < 4; sp++){
      s0 = s0 + *(const v4f*)(Ob + sp * 8192);
      s1 = s1 + *(const v4f*)(Ob + sp * 8192 + 4);
      li += lib[sp * 128];
    }
    float inv = 1.0f / li;
    v4i c = { pkbf(s0[0]*inv, s0[1]*inv), pkbf(s0[2]*inv, s0[3]*inv),
              pkbf(s1[0]*inv, s1[1]*inv), pkbf(s1[2]*inv, s1[3]*inv) };
    *(v4i*)&lA[rl][d8] = c;
  }
  // ---- stage B: Wvt with 16B-chunk XOR swizzle ----
  #pragma unroll
  for (int r = 0; r < 8; r++){
    int chunk = t + r * 512;             // 4096 = 512 rows x 8 chunks
    int row = chunk >> 3, c8 = chunk & 7;
    *(v8s*)&lB[row][(c8 ^ (row & 7)) * 8] =
        *(const v8s*)(Wvt + row * 64 + c8 * 8);
  }
  __syncthreads();

  int m0 = (w & 3) * 16;                 // row-group
  int colhalf = w >> 2;                  // 0/1 -> cols 0..255 / 256..511
  v8s A0 = *(const v8s*)&lA[m0 + l16][quad * 8];
  v8s A1 = *(const v8s*)&lA[m0 + l16][quad * 8 + 32];
  int ph = quad ^ (l16 & 7);
  v4f acc[16];
  #pragma unroll
  for (int cb = 0; cb < 16; cb++){
    int row = (colhalf * 16 + cb) * 16 + l16;
    const short* bp = &lB[row][0];
    v8s b0 = *(const v8s*)(bp + ph * 8);
    v8s b1 = *(const v8s*)(bp + (ph ^ 4) * 8);
    v4f z = (v4f){0.f, 0.f, 0.f, 0.f};
    z = __builtin_amdgcn_mfma_f32_16x16x32_bf16(A0, b0, z, 0, 0, 0);
    acc[cb] = __builtin_amdgcn_mfma_f32_16x16x32_bf16(A1, b1, z, 0, 0, 0);
  }
  #pragma unroll
  for (int cb = 0; cb < 16; cb++){
    int col = colhalf * 256 + cb * 16 + l16;
    float bvv = bv[col];
    #pragma unroll
    for (int r = 0; r < 4; r++){
      int gr = rowbase + m0 + quad * 4 + r;
      out[gr * 512 + col] = gamma * acc[cb][r] + bvv + x[gr * 512 + col];
    }
  }
}

// ---------------------------------------------------------------------------
// Kernel 3b (fallback, non-split path): out = gamma * ctx @ Wv + bv + x.
// ---------------------------------------------------------------------------
__global__ __launch_bounds__(256) void outproj_kernel(
    const unsigned short* __restrict__ ctx,
    const unsigned short* __restrict__ Wvt,  // [512][64] bf16
    const float* __restrict__ bv,
    const float* __restrict__ x,
    const float* __restrict__ gamma_p,
    float* __restrict__ out)
{
  __shared__ __align__(16) short lA[64][72];
  __shared__ __align__(16) short lB[128][72];
  int t = threadIdx.x;
  int w = t >> 6, lane = t & 63;
  int quad = lane >> 4, l16 = lane & 15;
  int rowbase = blockIdx.x * 64;
  int colbase = blockIdx.y * 128;
  float gamma = *gamma_p;

  #pragma unroll
  for (int r = 0; r < 2; r++){
    int chunk = t + r * 256;
    int row = chunk >> 3, c8 = chunk & 7;
    *(v8s*)&lA[row][c8 * 8] = *(const v8s*)(ctx + (rowbase + row) * 64 + c8 * 8);
  }
  #pragma unroll
  for (int r = 0; r < 4; r++){
    int chunk = t + r * 256;
    int row = chunk >> 3, c8 = chunk & 7;
    *(v8s*)&lB[row][c8 * 8] = *(const v8s*)(Wvt + (colbase + row) * 64 + c8 * 8);
  }
  __syncthreads();
  int m0 = w * 16;
  v8s A0 = *(const v8s*)&lA[m0 + l16][quad * 8];
  v8s A1 = *(const v8s*)&lA[m0 + l16][quad * 8 + 32];
  v4f acc[8];
  #pragma unroll
  for (int cb = 0; cb < 8; cb++){
    v8s b0 = *(const v8s*)&lB[cb * 16 + l16][quad * 8];
    v8s b1 = *(const v8s*)&lB[cb * 16 + l16][quad * 8 + 32];
    v4f z = (v4f){0.f, 0.f, 0.f, 0.f};
    z = __builtin_amdgcn_mfma_f32_16x16x32_bf16(A0, b0, z, 0, 0, 0);
    acc[cb] = __builtin_amdgcn_mfma_f32_16x16x32_bf16(A1, b1, z, 0, 0, 0);
  }
  #pragma unroll
  for (int cb = 0; cb < 8; cb++){
    int col = colbase + cb * 16 + l16;
    float bvv = bv[col];
    #pragma unroll
    for (int r = 0; r < 4; r++){
      int gr = rowbase + m0 + quad * 4 + r;
      out[gr * 512 + col] = gamma * acc[cb][r] + bvv + x[gr * 512 + col];
    }
  }
}

// ---------------------------------------------------------------------------
extern "C" void kernel_launch(void* const* d_in, const int* in_sizes, int n_in,
                              void* d_out, int out_size, void* d_ws, size_t ws_size,
                              hipStream_t stream) {
  const float* x   = (const float*)d_in[0];
  const float* Wf  = (const float*)d_in[1];
  const float* bf_ = (const float*)d_in[2];
  const float* Wg  = (const float*)d_in[3];
  const float* bg  = (const float*)d_in[4];
  const float* Wh  = (const float*)d_in[5];
  const float* bh  = (const float*)d_in[6];
  const float* Wv  = (const float*)d_in[7];
  const float* bv  = (const float*)d_in[8];
  const float* gam = (const float*)d_in[9];
  float* out = (float*)d_out;

  // workspace map (bytes):
  //   Wt   @ 0         (196608)
  //   Wvt  @ 196608    (65536)
  //   f    @ 262144    (4194304)
  //   g    @ 4456448   (4194304)
  //   ht   @ 8650752   (4194304)
  //   ctx  @ 12845056  (4194304)   (fallback path only)
  //   Opart @ 17039360 (33554432)   split-K partials [1024][128][64] f32
  //   lipart@ 50593792 (524288)     [1024][128] f32; total 51118080 (~48.8 MiB)
  char* ws = (char*)d_ws;
  unsigned short* Wt  = (unsigned short*)(ws);
  unsigned short* Wvt = (unsigned short*)(ws + 196608);
  unsigned short* f   = (unsigned short*)(ws + 262144);
  unsigned short* g   = (unsigned short*)(ws + 4456448);
  unsigned short* ht  = (unsigned short*)(ws + 8650752);
  unsigned short* ctx = (unsigned short*)(ws + 12845056);
  float* Opart  = (float*)(ws + 17039360);
  float* lipart = (float*)(ws + 50593792);

  transpose_w<<<512, 256, 0, stream>>>(Wf, Wg, Wh, Wv, Wt, Wvt);
  proj_kernel<<<512, 512, 0, stream>>>(x, Wt, bf_, bg, bh, f, g, ht);

  bool split = (ws_size >= (size_t)51118080);
  if (split){
    flash_kernel<<<dim3(32, 4, 8), 256, 0, stream>>>(f, g, ht, Opart, lipart, ctx, 16, 0);
    outfuse_kernel<<<512, 512, 0, stream>>>(Opart, lipart, Wvt, bv, x, gam, out);
  } else {
    flash_kernel<<<dim3(32, 1, 8), 256, 0, stream>>>(f, g, ht, nullptr, nullptr, ctx, 64, 1);
    outproj_kernel<<<dim3(512, 4), 256, 0, stream>>>(ctx, Wvt, bv, x, gam, out);
  }
}

// Round 10
// 201.784 us; speedup vs baseline: 1.0821x; 1.0047x over previous
//
#include <hip/hip_runtime.h>
#include <hip/hip_bf16.h>
#include <math.h>

// SAGAN attention block. Inputs/outputs fp32; internal matmuls bf16 MFMA.
// B=8, N=4096 (64x64 spatial), C=512, D=64.

typedef short v8s __attribute__((ext_vector_type(8)));
typedef unsigned short v4u __attribute__((ext_vector_type(4)));
typedef unsigned v4i __attribute__((ext_vector_type(4)));
typedef float v4f __attribute__((ext_vector_type(4)));

#define BB 8
#define NN 4096
#define CC 512
#define DD 64

__device__ __forceinline__ unsigned short f2bf(float f){
  union { float f; unsigned u; } v; v.f = f;
  unsigned r = (v.u + 0x7FFF + ((v.u >> 16) & 1)) >> 16;
  return (unsigned short)r;
}

// packed f32x2 -> bf16x2 (low = first arg)
#if __has_builtin(__builtin_amdgcn_cvt_pk_bf16_f32)
typedef __bf16 bf2_t __attribute__((ext_vector_type(2)));
__device__ __forceinline__ unsigned pkbf(float a, float b){
  bf2_t r = __builtin_amdgcn_cvt_pk_bf16_f32(a, b);
  union { bf2_t v; unsigned u; } c; c.v = r; return c.u;
}
#else
__device__ __forceinline__ unsigned pkbf(float a, float b){
  return (unsigned)f2bf(a) | ((unsigned)f2bf(b) << 16);
}
#endif

// raw v_exp_f32: skips OCML denormal-guard (cmp+cndmask+scale). Inputs below
// -126 flush to 0, which is exactly what softmax wants.
#if __has_builtin(__builtin_amdgcn_exp2f)
__device__ __forceinline__ float ex2(float x){ return __builtin_amdgcn_exp2f(x); }
#else
__device__ __forceinline__ float ex2(float x){ return exp2f(x); }
#endif

// async global->LDS, 16B per lane; LDS dest = wave-uniform base + lane*16
__device__ __forceinline__ void gload_lds16(const void* g, void* l){
  __builtin_amdgcn_global_load_lds(
      (const __attribute__((address_space(1))) void*)g,
      (__attribute__((address_space(3))) void*)l, 16, 0, 0);
}

// ---------------------------------------------------------------------------
// Kernel 0: convert fp32 weights to bf16, transposed (K-contiguous B-frags).
// ---------------------------------------------------------------------------
__global__ void transpose_w(const float* __restrict__ Wf,
                            const float* __restrict__ Wg,
                            const float* __restrict__ Wh,
                            const float* __restrict__ Wv,
                            unsigned short* __restrict__ Wt,
                            unsigned short* __restrict__ Wvt){
  int idx = blockIdx.x * 256 + threadIdx.x;
  if (idx < 3 * DD * CC){
    int p = idx / (DD * CC); int rem = idx % (DD * CC);
    int d = rem / CC; int c = rem % CC;
    const float* W = (p == 0) ? Wf : ((p == 1) ? Wg : Wh);
    Wt[idx] = f2bf(W[c * DD + d]);
  } else {
    int idx2 = idx - 3 * DD * CC;
    if (idx2 < CC * DD){
      int c = idx2 / DD; int d = idx2 % DD;
      Wvt[idx2] = f2bf(Wv[d * CC + c]);
    }
  }
}

// ---------------------------------------------------------------------------
// Kernel 1: fused projection GEMM.  f|g|h = x @ [Wf|Wg|Wh] + bias.
// f (query) pre-scaled by log2(e).  x converted fp32->bf16 with packed cvt.
// h written transposed (ht[b][d][n]) through an LDS transpose epilogue.
// 8-wave blocks (512 thr): wave w owns row-group (w>>1)*16, column-half w&1.
// Double-buffered LDS, one barrier per k-tile.
// ---------------------------------------------------------------------------
__global__ __launch_bounds__(512) void proj_kernel(
    const float* __restrict__ x,             // [32768][512] fp32
    const unsigned short* __restrict__ Wt,   // [192][512] bf16
    const float* __restrict__ bf_,
    const float* __restrict__ bg_,
    const float* __restrict__ bh_,
    unsigned short* __restrict__ f,
    unsigned short* __restrict__ g,
    unsigned short* __restrict__ ht)
{
  __shared__ __align__(16) short lA[2][64][72];
  __shared__ __align__(16) short lB[2][192][72];
  int t = threadIdx.x;                   // 0..511
  int w = t >> 6, lane = t & 63;
  int quad = lane >> 4, l16 = lane & 15;
  int rowbase = blockIdx.x * 64;
  int m0 = (w >> 1) * 16;                // row-group
  int ch = w & 1;                        // column half (6 col-blocks each)

  v4f acc[6];
  #pragma unroll
  for (int i = 0; i < 6; i++) acc[i] = (v4f){0.f, 0.f, 0.f, 0.f};

  // A staging: 512 threads x 8 floats (32B coalesced per thread)
  int arow = t >> 3, aq8 = t & 7;
  const float* xrow = x + (rowbase + arow) * 512 + aq8 * 8;

  v4f a0, a1;                            // prefetch registers (x)
  v8s br[3];                             // prefetch registers (Wt)

  auto load_regs = [&](int kt){
    const float* xp = xrow + kt * 64;
    a0 = *(const v4f*)(xp);
    a1 = *(const v4f*)(xp + 4);
    #pragma unroll
    for (int r = 0; r < 3; r++){
      int chunk = t + r * 512;           // 1536 chunks = 192 rows x 8
      int row = chunk >> 3, c8 = chunk & 7;
      br[r] = *(const v8s*)(Wt + row * 512 + kt * 64 + c8 * 8);
    }
  };
  auto write_lds = [&](int buf){
    v4i c0 = { pkbf(a0[0],a0[1]), pkbf(a0[2],a0[3]),
               pkbf(a1[0],a1[1]), pkbf(a1[2],a1[3]) };
    *(v4i*)&lA[buf][arow][aq8 * 8] = c0;
    #pragma unroll
    for (int r = 0; r < 3; r++){
      int chunk = t + r * 512;
      int row = chunk >> 3, c8 = chunk & 7;
      *(v8s*)&lB[buf][row][c8 * 8] = br[r];
    }
  };

  load_regs(0);
  write_lds(0);
  __syncthreads();
  for (int kt = 0; kt < 8; ++kt){
    int cur = kt & 1;
    if (kt < 7) load_regs(kt + 1);       // issue next tile's global loads
    v8s A0 = *(const v8s*)&lA[cur][m0 + l16][quad * 8];
    v8s A1 = *(const v8s*)&lA[cur][m0 + l16][quad * 8 + 32];
    #pragma unroll
    for (int cb = 0; cb < 6; ++cb){
      int cbg = ch * 6 + cb;
      v8s b0 = *(const v8s*)&lB[cur][cbg * 16 + l16][quad * 8];
      v8s b1 = *(const v8s*)&lB[cur][cbg * 16 + l16][quad * 8 + 32];
      acc[cb] = __builtin_amdgcn_mfma_f32_16x16x32_bf16(A0, b0, acc[cb], 0, 0, 0);
      acc[cb] = __builtin_amdgcn_mfma_f32_16x16x32_bf16(A1, b1, acc[cb], 0, 0, 0);
    }
    if (kt < 7) write_lds(cur ^ 1);      // land prefetch in alternate buffer
    __syncthreads();                     // one barrier per k-tile
  }

  // f and g: direct stores (cols 0..127; ch=0 covers 0..95, ch=1 96..127)
  #pragma unroll
  for (int cb = 0; cb < 6; ++cb){
    int cbg = ch * 6 + cb;
    if (cbg < 8){
      int col = cbg * 16 + l16;
      int p = col >> 6, d = col & 63;
      float bb = (p == 0) ? bf_[d] : bg_[d];
      #pragma unroll
      for (int r = 0; r < 4; r++){
        int gr = rowbase + m0 + quad * 4 + r;
        float val = acc[cb][r] + bb;
        if (p == 0) f[gr * 64 + d] = f2bf(val * 1.44269504f);  // log2(e) fold
        else        g[gr * 64 + d] = f2bf(val);
      }
    }
  }

  // h (cols 128..191, all in ch=1 waves, cb 2..5): LDS transpose -> ht
  short (*lT)[65] = (short(*)[65])lB;
  if (ch == 1){
    #pragma unroll
    for (int cb = 2; cb < 6; ++cb){
      int d = (cb - 2) * 16 + l16;
      float bb = bh_[d];
      #pragma unroll
      for (int r = 0; r < 4; r++)
        lT[m0 + quad * 4 + r][d] = (short)f2bf(acc[cb][r] + bb);
    }
  }
  __syncthreads();
  {
    int dd = t >> 3, nseg = t & 7;       // 64 d x 8 row-segments of 8
    v8s h0;
    #pragma unroll
    for (int i = 0; i < 8; i++)
      h0[i] = lT[nseg * 8 + i][dd];
    int bidx = rowbase >> 12;
    int n0 = (rowbase & 4095) + nseg * 8;
    unsigned short* hp = ht + ((size_t)(bidx * 64 + dd)) * 4096 + n0;
    *(v8s*)hp = h0;
  }
}

// ---------------------------------------------------------------------------
// Kernel 2: flash attention, S^T form, no-max softmax (exp2 domain).
// Block = 128 Q rows (4 waves x 32, two 16-row groups per wave), niter
// key-tiles of 64 (must be EVEN).
// K/V tiles: double-buffered unpadded 64x64 in LDS, 16B-chunk XOR swizzle
// (c ^= row&7), staged via global_load_lds (swizzle folded into source addr).
// 2-phase pipeline: stage(next buf) -> compute(cur buf) -> one barrier/tile.
// Row-sums computed on the matrix pipe (all-ones B operand).
// Round 10: lP shrunk to 1 KiB/wave ([4][4][16][8]).  P round-trips in TWO
// half-chunk passes: chunks 0-3 (written by cb 0,1) -> read PA0 -> overwrite
// with chunks 4-7 (cb 2,3) -> read PA1.  Slot = chunk&3; both reads hit slot
// `quad`.  Same-wave DS ordering keeps it safe (same property as the gi
// reuse).  LDS total 36864 B -> 4 blocks/CU with 16 KiB margin, eliminating
// the exact-fit failure (40960*4 = 163840 = exactly 160 KiB left no room for
// any per-WG reserve -> only 3 blocks resident -> a 256-block tail ROUND that
// pinned flash at ~58 us across rounds 4-9).
// V fragments hoisted to registers once per tile, reused by both q-groups.
// ---------------------------------------------------------------------------
__global__ __launch_bounds__(256) void flash_kernel(
    const unsigned short* __restrict__ f,   // Q [B][N][64] (prescaled log2e)
    const unsigned short* __restrict__ g,   // K [B][N][64]
    const unsigned short* __restrict__ ht,  // V^T [B][64][N]
    float* __restrict__ Opart,              // [1024][128][64] fp32 (split)
    float* __restrict__ lipart,             // [1024][128]
    unsigned short* __restrict__ ctx,       // [B][N][64] (direct)
    int niter, int direct)
{
  __shared__ __align__(16) short lK[2][64 * 64];    // [buf][key][d] swizzled
  __shared__ __align__(16) short lV[2][64 * 64];    // [buf][d][key] swizzled
  __shared__ __align__(16) short lP[4][4][16][8];   // per-wave HALF-P buffer
  int t = threadIdx.x;
  int w = t >> 6, lane = t & 63;
  int quad = lane >> 4, l16 = lane & 15;
  int qt = blockIdx.x, sp = blockIdx.y, b = blockIdx.z;
  int q0 = qt * 128;
  int m0 = w * 32;                       // wave's q offset within block

  const unsigned short* fb = f  + b * NN * 64;
  const unsigned short* gb = g  + b * NN * 64;
  const unsigned short* hb = ht + b * 64 * NN;

  // Q as B-operand fragment (B[k=d][n=q]): lane n=l16=q, k=quad*8+j.
  // Two 16-row groups per wave.
  const unsigned short* qbase = fb + (q0 + m0 + l16) * 64;
  v8s QB00 = *(const v8s*)(qbase + quad * 8);
  v8s QB01 = *(const v8s*)(qbase + quad * 8 + 32);
  v8s QB10 = *(const v8s*)(qbase + 16 * 64 + quad * 8);
  v8s QB11 = *(const v8s*)(qbase + 16 * 64 + quad * 8 + 32);

  // staging: wave w fills LDS bytes [w*2048, w*2048+2048) in 2 calls of 1024B
  int j0 = sp * niter;
  const char* srcK[2]; const char* srcV[2];
  char* dstK[2][2]; char* dstV[2][2];
  #pragma unroll
  for (int k = 0; k < 2; k++){
    int row = w * 16 + k * 8 + (lane >> 3);
    int c = (lane & 7) ^ (row & 7);            // XOR swizzle on source
    srcK[k] = (const char*)gb + (size_t)j0 * 8192 + row * 128 + c * 16;
    srcV[k] = (const char*)hb + (size_t)row * 8192 + (size_t)j0 * 128 + c * 16;
    #pragma unroll
    for (int b2 = 0; b2 < 2; b2++){
      dstK[b2][k] = (char*)lK[b2] + w * 2048 + k * 1024;
      dstV[b2][k] = (char*)lV[b2] + w * 2048 + k * 1024;
    }
  }

  // loop-invariant LDS frag addresses per buffer (logical chunk ph / ph^4)
  int ph = quad ^ (l16 & 7);
  const short* kA0[2]; const short* kA1[2];
  const short* vB0[2]; const short* vB1[2];
  #pragma unroll
  for (int b2 = 0; b2 < 2; b2++){
    kA0[b2] = lK[b2] + l16 * 64 + ph * 8;
    kA1[b2] = lK[b2] + l16 * 64 + (ph ^ 4) * 8;
    vB0[b2] = lV[b2] + l16 * 64 + ph * 8;
    vB1[b2] = lV[b2] + l16 * 64 + (ph ^ 4) * 8;
  }

  v8s ones;                                   // bf16 1.0 broadcast (B-frag)
  #pragma unroll
  for (int i = 0; i < 8; i++) ones[i] = (short)0x3F80;

  v4f rz[2];                                  // rowsum acc per group
  rz[0] = (v4f){0.f, 0.f, 0.f, 0.f};
  rz[1] = (v4f){0.f, 0.f, 0.f, 0.f};
  v4f O[2][4];
  #pragma unroll
  for (int gi = 0; gi < 2; gi++)
    #pragma unroll
    for (int cb = 0; cb < 4; cb++) O[gi][cb] = (v4f){0.f, 0.f, 0.f, 0.f};

  auto stage = [&](int b2){
    #pragma unroll
    for (int k = 0; k < 2; k++){
      gload_lds16(srcK[k], dstK[b2][k]);
      gload_lds16(srcV[k], dstV[b2][k]);
      srcK[k] += 8192; srcV[k] += 128;
    }
  };

  auto compute = [&](int b2){
    // S^T(64key x 32q) = K · Q^T : st[g][cb][r] = S[q][key=cb*16+quad*4+r]
    v4f st[2][4];
    __builtin_amdgcn_s_setprio(1);
    #pragma unroll
    for (int cb = 0; cb < 4; cb++){
      v8s a0 = *(const v8s*)(kA0[b2] + cb * 1024);
      v8s a1 = *(const v8s*)(kA1[b2] + cb * 1024);
      v4f z0 = (v4f){0.f, 0.f, 0.f, 0.f};
      z0 = __builtin_amdgcn_mfma_f32_16x16x32_bf16(a0, QB00, z0, 0, 0, 0);
      st[0][cb] = __builtin_amdgcn_mfma_f32_16x16x32_bf16(a1, QB01, z0, 0, 0, 0);
      v4f z1 = (v4f){0.f, 0.f, 0.f, 0.f};
      z1 = __builtin_amdgcn_mfma_f32_16x16x32_bf16(a0, QB10, z1, 0, 0, 0);
      st[1][cb] = __builtin_amdgcn_mfma_f32_16x16x32_bf16(a1, QB11, z1, 0, 0, 0);
    }
    __builtin_amdgcn_s_setprio(0);

    // p = 2^s (raw v_exp), pack pairs via perm (bf16 trunc), b64 store to lP.
    // Half h covers original chunks 4h..4h+3 (cb = 2h, 2h+1); stored at
    // slot chunk&3 = (cb&1)*2 + (quad>>1).  Lane's 4-key run at (quad&1)*4.
    auto packhalf = [&](int gi, int h){
      #pragma unroll
      for (int cc = 0; cc < 2; cc++){
        int cb = 2 * h + cc;
        float p0 = ex2(st[gi][cb][0]);
        float p1 = ex2(st[gi][cb][1]);
        float p2 = ex2(st[gi][cb][2]);
        float p3 = ex2(st[gi][cb][3]);
        unsigned d0 = __builtin_amdgcn_perm(__float_as_uint(p1), __float_as_uint(p0), 0x07060302u);
        unsigned d1 = __builtin_amdgcn_perm(__float_as_uint(p3), __float_as_uint(p2), 0x07060302u);
        uint2 pk; pk.x = d0; pk.y = d1;
        *(uint2*)&lP[w][cc * 2 + (quad >> 1)][l16][(quad & 1) * 4] = pk;
      }
    };

    // P round trips through the 1 KiB half-buffer; same-wave DS ordering
    // guarantees each read sees its half's writes and precedes the next
    // half's overwrite.  Both reads target slot `quad`.
    packhalf(0, 0);
    v8s PA00 = *(const v8s*)&lP[w][quad][l16][0];   // chunks 0-3 of gi0
    packhalf(0, 1);
    v8s PA01 = *(const v8s*)&lP[w][quad][l16][0];   // chunks 4-7 of gi0
    packhalf(1, 0);
    v8s PA10 = *(const v8s*)&lP[w][quad][l16][0];   // chunks 0-3 of gi1
    packhalf(1, 1);
    v8s PA11 = *(const v8s*)&lP[w][quad][l16][0];   // chunks 4-7 of gi1

    // V fragments: read ONCE, reused by both q-groups (st[] is dead here,
    // so vb[] lands in freed registers; peak pressure unchanged).
    v8s vb[4][2];
    #pragma unroll
    for (int cb = 0; cb < 4; cb++){
      vb[cb][0] = *(const v8s*)(vB0[b2] + cb * 1024);
      vb[cb][1] = *(const v8s*)(vB1[b2] + cb * 1024);
    }

    __builtin_amdgcn_s_setprio(1);
    rz[0] = __builtin_amdgcn_mfma_f32_16x16x32_bf16(PA00, ones, rz[0], 0, 0, 0);
    rz[0] = __builtin_amdgcn_mfma_f32_16x16x32_bf16(PA01, ones, rz[0], 0, 0, 0);
    #pragma unroll
    for (int cb = 0; cb < 4; cb++){
      O[0][cb] = __builtin_amdgcn_mfma_f32_16x16x32_bf16(PA00, vb[cb][0], O[0][cb], 0, 0, 0);
      O[0][cb] = __builtin_amdgcn_mfma_f32_16x16x32_bf16(PA01, vb[cb][1], O[0][cb], 0, 0, 0);
    }
    rz[1] = __builtin_amdgcn_mfma_f32_16x16x32_bf16(PA10, ones, rz[1], 0, 0, 0);
    rz[1] = __builtin_amdgcn_mfma_f32_16x16x32_bf16(PA11, ones, rz[1], 0, 0, 0);
    #pragma unroll
    for (int cb = 0; cb < 4; cb++){
      O[1][cb] = __builtin_amdgcn_mfma_f32_16x16x32_bf16(PA10, vb[cb][0], O[1][cb], 0, 0, 0);
      O[1][cb] = __builtin_amdgcn_mfma_f32_16x16x32_bf16(PA11, vb[cb][1], O[1][cb], 0, 0, 0);
    }
    __builtin_amdgcn_s_setprio(0);
  };

  // 2-phase pipeline, niter even: prologue fills buf0; loop unrolled by 2.
  stage(0);
  __syncthreads();                 // buf0 ready (syncthreads drains vmcnt)
  for (int jj = 0; jj < niter; jj += 2){
    stage(1);                      // prefetch tile jj+1 under compute of jj
    compute(0);
    __syncthreads();               // buf1 ready; buf0 reads done
    if (jj + 2 < niter) stage(0);  // prefetch tile jj+2
    compute(1);
    __syncthreads();               // buf0 ready; buf1 reads done
  }

  if (direct){
    #pragma unroll
    for (int gi = 0; gi < 2; gi++){
      float inv[4];
      #pragma unroll
      for (int r = 0; r < 4; r++)
        inv[r] = 1.0f / rz[gi][r];
      #pragma unroll
      for (int cb = 0; cb < 4; cb++)
        #pragma unroll
        for (int r = 0; r < 4; r++){
          int row = q0 + m0 + gi * 16 + quad * 4 + r;
          ctx[(b * NN + row) * 64 + cb * 16 + l16] = f2bf(O[gi][cb][r] * inv[r]);
        }
    }
  } else {
    int bf = (b * 32 + qt) * 4 + sp;
    if (l16 == 0){
      #pragma unroll
      for (int gi = 0; gi < 2; gi++)
        #pragma unroll
        for (int r = 0; r < 4; r++)
          lipart[bf * 128 + m0 + gi * 16 + quad * 4 + r] = rz[gi][r];
    }
    float* Ob = Opart + (size_t)bf * 8192;
    #pragma unroll
    for (int gi = 0; gi < 2; gi++)
      #pragma unroll
      for (int cb = 0; cb < 4; cb++)
        #pragma unroll
        for (int r = 0; r < 4; r++)
          Ob[(m0 + gi * 16 + quad * 4 + r) * 64 + cb * 16 + l16] = O[gi][cb][r];
  }
}

// ---------------------------------------------------------------------------
// Kernel 3 (split path): FUSED reduce + outproj.
// out = gamma * (sum_sp Opart / li) @ Wv + bv + x.  512 blocks x 512 thr.
// Block = 64 rows x all 512 cols.  ctx never touches HBM:
//   stage A: normalize Opart/lipart in-register -> bf16 A-tile in LDS.
//   stage B: full Wvt (64 KB) with 16B-chunk XOR swizzle (conflict-free
//            B-frag reads from unpadded [512][64]).
// 8 waves: wave w -> row-group (w&3)*16, col-half w>>2 (16 col-blocks each).
// LDS = 9.2 + 64 KB = 73.2 KB -> 2 blocks/CU.
// ---------------------------------------------------------------------------
__global__ __launch_bounds__(512) void outfuse_kernel(
    const float* __restrict__ Opart,         // [256 grp][4 sp][128][64]
    const float* __restrict__ lipart,        // [256 grp][4 sp][128]
    const unsigned short* __restrict__ Wvt,  // [512][64] bf16
    const float* __restrict__ bv,
    const float* __restrict__ x,
    const float* __restrict__ gamma_p,
    float* __restrict__ out)
{
  __shared__ __align__(16) short lA[64][72];
  __shared__ __align__(16) short lB[512][64];   // XOR-swizzled 16B chunks
  int t = threadIdx.x;                   // 0..511
  int lane = t & 63;
  int w = t >> 6;
  int quad = lane >> 4, l16 = lane & 15;
  int rowbase = blockIdx.x * 64;
  float gamma = *gamma_p;

  // ---- stage A: ctx tile from split-K partials (no HBM round trip) ----
  {
    int rl = t >> 3, d8 = (t & 7) * 8;   // row-local 0..63, d offset 0..56
    int group = rowbase >> 7;            // Opart group = 128 global rows
    int inrow = (rowbase & 127) + rl;
    const float* Ob  = Opart  + (size_t)group * 32768 + inrow * 64 + d8;
    const float* lib = lipart + group * 512 + inrow;
    v4f s0 = *(const v4f*)(Ob);
    v4f s1 = *(const v4f*)(Ob + 4);
    float li = lib[0];
    #pragma unroll
    for (int sp = 1; sp < 4; sp++){
      s0 = s0 + *(const v4f*)(Ob + sp * 8192);
      s1 = s1 + *(const v4f*)(Ob + sp * 8192 + 4);
      li += lib[sp * 128];
    }
    float inv = 1.0f / li;
    v4i c = { pkbf(s0[0]*inv, s0[1]*inv), pkbf(s0[2]*inv, s0[3]*inv),
              pkbf(s1[0]*inv, s1[1]*inv), pkbf(s1[2]*inv, s1[3]*inv) };
    *(v4i*)&lA[rl][d8] = c;
  }
  // ---- stage B: Wvt with 16B-chunk XOR swizzle ----
  #pragma unroll
  for (int r = 0; r < 8; r++){
    int chunk = t + r * 512;             // 4096 = 512 rows x 8 chunks
    int row = chunk >> 3, c8 = chunk & 7;
    *(v8s*)&lB[row][(c8 ^ (row & 7)) * 8] =
        *(const v8s*)(Wvt + row * 64 + c8 * 8);
  }
  __syncthreads();

  int m0 = (w & 3) * 16;                 // row-group
  int colhalf = w >> 2;                  // 0/1 -> cols 0..255 / 256..511
  v8s A0 = *(const v8s*)&lA[m0 + l16][quad * 8];
  v8s A1 = *(const v8s*)&lA[m0 + l16][quad * 8 + 32];
  int ph = quad ^ (l16 & 7);
  v4f acc[16];
  #pragma unroll
  for (int cb = 0; cb < 16; cb++){
    int row = (colhalf * 16 + cb) * 16 + l16;
    const short* bp = &lB[row][0];
    v8s b0 = *(const v8s*)(bp + ph * 8);
    v8s b1 = *(const v8s*)(bp + (ph ^ 4) * 8);
    v4f z = (v4f){0.f, 0.f, 0.f, 0.f};
    z = __builtin_amdgcn_mfma_f32_16x16x32_bf16(A0, b0, z, 0, 0, 0);
    acc[cb] = __builtin_amdgcn_mfma_f32_16x16x32_bf16(A1, b1, z, 0, 0, 0);
  }
  #pragma unroll
  for (int cb = 0; cb < 16; cb++){
    int col = colhalf * 256 + cb * 16 + l16;
    float bvv = bv[col];
    #pragma unroll
    for (int r = 0; r < 4; r++){
      int gr = rowbase + m0 + quad * 4 + r;
      out[gr * 512 + col] = gamma * acc[cb][r] + bvv + x[gr * 512 + col];
    }
  }
}

// ---------------------------------------------------------------------------
// Kernel 3b (fallback, non-split path): out = gamma * ctx @ Wv + bv + x.
// ---------------------------------------------------------------------------
__global__ __launch_bounds__(256) void outproj_kernel(
    const unsigned short* __restrict__ ctx,
    const unsigned short* __restrict__ Wvt,  // [512][64] bf16
    const float* __restrict__ bv,
    const float* __restrict__ x,
    const float* __restrict__ gamma_p,
    float* __restrict__ out)
{
  __shared__ __align__(16) short lA[64][72];
  __shared__ __align__(16) short lB[128][72];
  int t = threadIdx.x;
  int w = t >> 6, lane = t & 63;
  int quad = lane >> 4, l16 = lane & 15;
  int rowbase = blockIdx.x * 64;
  int colbase = blockIdx.y * 128;
  float gamma = *gamma_p;

  #pragma unroll
  for (int r = 0; r < 2; r++){
    int chunk = t + r * 256;
    int row = chunk >> 3, c8 = chunk & 7;
    *(v8s*)&lA[row][c8 * 8] = *(const v8s*)(ctx + (rowbase + row) * 64 + c8 * 8);
  }
  #pragma unroll
  for (int r = 0; r < 4; r++){
    int chunk = t + r * 256;
    int row = chunk >> 3, c8 = chunk & 7;
    *(v8s*)&lB[row][c8 * 8] = *(const v8s*)(Wvt + (colbase + row) * 64 + c8 * 8);
  }
  __syncthreads();
  int m0 = w * 16;
  v8s A0 = *(const v8s*)&lA[m0 + l16][quad * 8];
  v8s A1 = *(const v8s*)&lA[m0 + l16][quad * 8 + 32];
  v4f acc[8];
  #pragma unroll
  for (int cb = 0; cb < 8; cb++){
    v8s b0 = *(const v8s*)&lB[cb * 16 + l16][quad * 8];
    v8s b1 = *(const v8s*)&lB[cb * 16 + l16][quad * 8 + 32];
    v4f z = (v4f){0.f, 0.f, 0.f, 0.f};
    z = __builtin_amdgcn_mfma_f32_16x16x32_bf16(A0, b0, z, 0, 0, 0);
    acc[cb] = __builtin_amdgcn_mfma_f32_16x16x32_bf16(A1, b1, z, 0, 0, 0);
  }
  #pragma unroll
  for (int cb = 0; cb < 8; cb++){
    int col = colbase + cb * 16 + l16;
    float bvv = bv[col];
    #pragma unroll
    for (int r = 0; r < 4; r++){
      int gr = rowbase + m0 + quad * 4 + r;
      out[gr * 512 + col] = gamma * acc[cb][r] + bvv + x[gr * 512 + col];
    }
  }
}

// ---------------------------------------------------------------------------
extern "C" void kernel_launch(void* const* d_in, const int* in_sizes, int n_in,
                              void* d_out, int out_size, void* d_ws, size_t ws_size,
                              hipStream_t stream) {
  const float* x   = (const float*)d_in[0];
  const float* Wf  = (const float*)d_in[1];
  const float* bf_ = (const float*)d_in[2];
  const float* Wg  = (const float*)d_in[3];
  const float* bg  = (const float*)d_in[4];
  const float* Wh  = (const float*)d_in[5];
  const float* bh  = (const float*)d_in[6];
  const float* Wv  = (const float*)d_in[7];
  const float* bv  = (const float*)d_in[8];
  const float* gam = (const float*)d_in[9];
  float* out = (float*)d_out;

  // workspace map (bytes):
  //   Wt   @ 0         (196608)
  //   Wvt  @ 196608    (65536)
  //   f    @ 262144    (4194304)
  //   g    @ 4456448   (4194304)
  //   ht   @ 8650752   (4194304)
  //   ctx  @ 12845056  (4194304)   (fallback path only)
  //   Opart @ 17039360 (33554432)   split-K partials [1024][128][64] f32
  //   lipart@ 50593792 (524288)     [1024][128] f32; total 51118080 (~48.8 MiB)
  char* ws = (char*)d_ws;
  unsigned short* Wt  = (unsigned short*)(ws);
  unsigned short* Wvt = (unsigned short*)(ws + 196608);
  unsigned short* f   = (unsigned short*)(ws + 262144);
  unsigned short* g   = (unsigned short*)(ws + 4456448);
  unsigned short* ht  = (unsigned short*)(ws + 8650752);
  unsigned short* ctx = (unsigned short*)(ws + 12845056);
  float* Opart  = (float*)(ws + 17039360);
  float* lipart = (float*)(ws + 50593792);

  transpose_w<<<512, 256, 0, stream>>>(Wf, Wg, Wh, Wv, Wt, Wvt);
  proj_kernel<<<512, 512, 0, stream>>>(x, Wt, bf_, bg, bh, f, g, ht);

  bool split = (ws_size >= (size_t)51118080);
  if (split){
    flash_kernel<<<dim3(32, 4, 8), 256, 0, stream>>>(f, g, ht, Opart, lipart, ctx, 16, 0);
    outfuse_kernel<<<512, 512, 0, stream>>>(Opart, lipart, Wvt, bv, x, gam, out);
  } else {
    flash_kernel<<<dim3(32, 1, 8), 256, 0, stream>>>(f, g, ht, nullptr, nullptr, ctx, 64, 1);
    outproj_kernel<<<dim3(512, 4), 256, 0, stream>>>(ctx, Wvt, bv, x, gam, out);
  }
}

// Round 11
// 201.215 us; speedup vs baseline: 1.0851x; 1.0028x over previous
//
#include <hip/hip_runtime.h>
#include <hip/hip_bf16.h>
#include <math.h>

// SAGAN attention block. Inputs/outputs fp32; internal matmuls bf16 MFMA.
// B=8, N=4096 (64x64 spatial), C=512, D=64.

typedef short v8s __attribute__((ext_vector_type(8)));
typedef unsigned short v4u __attribute__((ext_vector_type(4)));
typedef unsigned v4i __attribute__((ext_vector_type(4)));
typedef float v4f __attribute__((ext_vector_type(4)));

#define BB 8
#define NN 4096
#define CC 512
#define DD 64

__device__ __forceinline__ unsigned short f2bf(float f){
  union { float f; unsigned u; } v; v.f = f;
  unsigned r = (v.u + 0x7FFF + ((v.u >> 16) & 1)) >> 16;
  return (unsigned short)r;
}

// packed f32x2 -> bf16x2 (low = first arg)
#if __has_builtin(__builtin_amdgcn_cvt_pk_bf16_f32)
typedef __bf16 bf2_t __attribute__((ext_vector_type(2)));
__device__ __forceinline__ unsigned pkbf(float a, float b){
  bf2_t r = __builtin_amdgcn_cvt_pk_bf16_f32(a, b);
  union { bf2_t v; unsigned u; } c; c.v = r; return c.u;
}
#else
__device__ __forceinline__ unsigned pkbf(float a, float b){
  return (unsigned)f2bf(a) | ((unsigned)f2bf(b) << 16);
}
#endif

// raw v_exp_f32: skips OCML denormal-guard (cmp+cndmask+scale). Inputs below
// -126 flush to 0, which is exactly what softmax wants.
#if __has_builtin(__builtin_amdgcn_exp2f)
__device__ __forceinline__ float ex2(float x){ return __builtin_amdgcn_exp2f(x); }
#else
__device__ __forceinline__ float ex2(float x){ return exp2f(x); }
#endif

// async global->LDS, 16B per lane; LDS dest = wave-uniform base + lane*16
__device__ __forceinline__ void gload_lds16(const void* g, void* l){
  __builtin_amdgcn_global_load_lds(
      (const __attribute__((address_space(1))) void*)g,
      (__attribute__((address_space(3))) void*)l, 16, 0, 0);
}

// ---------------------------------------------------------------------------
// Kernel 0: convert fp32 weights to bf16, transposed (K-contiguous B-frags).
// ---------------------------------------------------------------------------
__global__ void transpose_w(const float* __restrict__ Wf,
                            const float* __restrict__ Wg,
                            const float* __restrict__ Wh,
                            const float* __restrict__ Wv,
                            unsigned short* __restrict__ Wt,
                            unsigned short* __restrict__ Wvt){
  int idx = blockIdx.x * 256 + threadIdx.x;
  if (idx < 3 * DD * CC){
    int p = idx / (DD * CC); int rem = idx % (DD * CC);
    int d = rem / CC; int c = rem % CC;
    const float* W = (p == 0) ? Wf : ((p == 1) ? Wg : Wh);
    Wt[idx] = f2bf(W[c * DD + d]);
  } else {
    int idx2 = idx - 3 * DD * CC;
    if (idx2 < CC * DD){
      int c = idx2 / DD; int d = idx2 % DD;
      Wvt[idx2] = f2bf(Wv[d * CC + c]);
    }
  }
}

// ---------------------------------------------------------------------------
// Kernel 1: fused projection GEMM.  f|g|h = x @ [Wf|Wg|Wh] + bias.
// f (query) pre-scaled by log2(e).  x converted fp32->bf16 with packed cvt.
// h written transposed (ht[b][d][n]) through an LDS transpose epilogue.
// 8-wave blocks (512 thr): wave w owns row-group (w>>1)*16, column-half w&1.
// Double-buffered LDS, one barrier per k-tile.
// ---------------------------------------------------------------------------
__global__ __launch_bounds__(512) void proj_kernel(
    const float* __restrict__ x,             // [32768][512] fp32
    const unsigned short* __restrict__ Wt,   // [192][512] bf16
    const float* __restrict__ bf_,
    const float* __restrict__ bg_,
    const float* __restrict__ bh_,
    unsigned short* __restrict__ f,
    unsigned short* __restrict__ g,
    unsigned short* __restrict__ ht)
{
  __shared__ __align__(16) short lA[2][64][72];
  __shared__ __align__(16) short lB[2][192][72];
  int t = threadIdx.x;                   // 0..511
  int w = t >> 6, lane = t & 63;
  int quad = lane >> 4, l16 = lane & 15;
  int rowbase = blockIdx.x * 64;
  int m0 = (w >> 1) * 16;                // row-group
  int ch = w & 1;                        // column half (6 col-blocks each)

  v4f acc[6];
  #pragma unroll
  for (int i = 0; i < 6; i++) acc[i] = (v4f){0.f, 0.f, 0.f, 0.f};

  // A staging: 512 threads x 8 floats (32B coalesced per thread)
  int arow = t >> 3, aq8 = t & 7;
  const float* xrow = x + (rowbase + arow) * 512 + aq8 * 8;

  v4f a0, a1;                            // prefetch registers (x)
  v8s br[3];                             // prefetch registers (Wt)

  auto load_regs = [&](int kt){
    const float* xp = xrow + kt * 64;
    a0 = *(const v4f*)(xp);
    a1 = *(const v4f*)(xp + 4);
    #pragma unroll
    for (int r = 0; r < 3; r++){
      int chunk = t + r * 512;           // 1536 chunks = 192 rows x 8
      int row = chunk >> 3, c8 = chunk & 7;
      br[r] = *(const v8s*)(Wt + row * 512 + kt * 64 + c8 * 8);
    }
  };
  auto write_lds = [&](int buf){
    v4i c0 = { pkbf(a0[0],a0[1]), pkbf(a0[2],a0[3]),
               pkbf(a1[0],a1[1]), pkbf(a1[2],a1[3]) };
    *(v4i*)&lA[buf][arow][aq8 * 8] = c0;
    #pragma unroll
    for (int r = 0; r < 3; r++){
      int chunk = t + r * 512;
      int row = chunk >> 3, c8 = chunk & 7;
      *(v8s*)&lB[buf][row][c8 * 8] = br[r];
    }
  };

  load_regs(0);
  write_lds(0);
  __syncthreads();
  for (int kt = 0; kt < 8; ++kt){
    int cur = kt & 1;
    if (kt < 7) load_regs(kt + 1);       // issue next tile's global loads
    v8s A0 = *(const v8s*)&lA[cur][m0 + l16][quad * 8];
    v8s A1 = *(const v8s*)&lA[cur][m0 + l16][quad * 8 + 32];
    #pragma unroll
    for (int cb = 0; cb < 6; ++cb){
      int cbg = ch * 6 + cb;
      v8s b0 = *(const v8s*)&lB[cur][cbg * 16 + l16][quad * 8];
      v8s b1 = *(const v8s*)&lB[cur][cbg * 16 + l16][quad * 8 + 32];
      acc[cb] = __builtin_amdgcn_mfma_f32_16x16x32_bf16(A0, b0, acc[cb], 0, 0, 0);
      acc[cb] = __builtin_amdgcn_mfma_f32_16x16x32_bf16(A1, b1, acc[cb], 0, 0, 0);
    }
    if (kt < 7) write_lds(cur ^ 1);      // land prefetch in alternate buffer
    __syncthreads();                     // one barrier per k-tile
  }

  // f and g: direct stores (cols 0..127; ch=0 covers 0..95, ch=1 96..127)
  #pragma unroll
  for (int cb = 0; cb < 6; ++cb){
    int cbg = ch * 6 + cb;
    if (cbg < 8){
      int col = cbg * 16 + l16;
      int p = col >> 6, d = col & 63;
      float bb = (p == 0) ? bf_[d] : bg_[d];
      #pragma unroll
      for (int r = 0; r < 4; r++){
        int gr = rowbase + m0 + quad * 4 + r;
        float val = acc[cb][r] + bb;
        if (p == 0) f[gr * 64 + d] = f2bf(val * 1.44269504f);  // log2(e) fold
        else        g[gr * 64 + d] = f2bf(val);
      }
    }
  }

  // h (cols 128..191, all in ch=1 waves, cb 2..5): LDS transpose -> ht
  short (*lT)[65] = (short(*)[65])lB;
  if (ch == 1){
    #pragma unroll
    for (int cb = 2; cb < 6; ++cb){
      int d = (cb - 2) * 16 + l16;
      float bb = bh_[d];
      #pragma unroll
      for (int r = 0; r < 4; r++)
        lT[m0 + quad * 4 + r][d] = (short)f2bf(acc[cb][r] + bb);
    }
  }
  __syncthreads();
  {
    int dd = t >> 3, nseg = t & 7;       // 64 d x 8 row-segments of 8
    v8s h0;
    #pragma unroll
    for (int i = 0; i < 8; i++)
      h0[i] = lT[nseg * 8 + i][dd];
    int bidx = rowbase >> 12;
    int n0 = (rowbase & 4095) + nseg * 8;
    unsigned short* hp = ht + ((size_t)(bidx * 64 + dd)) * 4096 + n0;
    *(v8s*)hp = h0;
  }
}

// ---------------------------------------------------------------------------
// Kernel 2: flash attention, S^T form, no-max softmax (exp2 domain).
// Block = 128 Q rows (4 waves x 32, two 16-row groups per wave).
// Round 11: TRIPLE-buffered K/V with 2-deep prefetch and COUNTED vmcnt
// (T3+T4).  Rounds 3-10 were pinned at 56-59 us regardless of per-iter
// work: the invariant was the 1-deep prefetch + __syncthreads full drain
// (vmcnt(0)) -- each tile's 16 KB of global_load_lds had only ONE compute
// phase (~600-800 cyc) to cover ~500-900 cyc of L2/HBM latency, so every
// barrier exposed staging latency.  Now: keep tiles j+1 AND j+2 in flight;
// at tile j wait `s_waitcnt vmcnt(4)` (drain j's 4 loads, keep j+2's 4)
// then raw s_barrier.  Staging gets TWO tile periods -> zero exposed.
// Safety: vmcnt-before-barrier guarantees all waves' stage-j landed before
// any wave reads buf j; the same barrier orders tile j-1's reads before
// stage(j+2) overwrites that buffer.  sched_barrier(0) fences (rule #18).
// niter in {16,64}, both == 1 mod 3 -> static-buffer remainder slot.
// lP 1 KiB/wave half-buffer (round 10).  LDS 53248 B -> 3 blocks/CU.
// ---------------------------------------------------------------------------
__global__ __launch_bounds__(256) void flash_kernel(
    const unsigned short* __restrict__ f,   // Q [B][N][64] (prescaled log2e)
    const unsigned short* __restrict__ g,   // K [B][N][64]
    const unsigned short* __restrict__ ht,  // V^T [B][64][N]
    float* __restrict__ Opart,              // [1024][128][64] fp32 (split)
    float* __restrict__ lipart,             // [1024][128]
    unsigned short* __restrict__ ctx,       // [B][N][64] (direct)
    int niter, int direct)
{
  __shared__ __align__(16) short lK[3][64 * 64];    // [buf][key][d] swizzled
  __shared__ __align__(16) short lV[3][64 * 64];    // [buf][d][key] swizzled
  __shared__ __align__(16) short lP[4][4][16][8];   // per-wave HALF-P buffer
  int t = threadIdx.x;
  int w = t >> 6, lane = t & 63;
  int quad = lane >> 4, l16 = lane & 15;
  int qt = blockIdx.x, sp = blockIdx.y, b = blockIdx.z;
  int q0 = qt * 128;
  int m0 = w * 32;                       // wave's q offset within block

  const unsigned short* fb = f  + b * NN * 64;
  const unsigned short* gb = g  + b * NN * 64;
  const unsigned short* hb = ht + b * 64 * NN;

  // Q as B-operand fragment (B[k=d][n=q]): lane n=l16=q, k=quad*8+j.
  // Two 16-row groups per wave.
  const unsigned short* qbase = fb + (q0 + m0 + l16) * 64;
  v8s QB00 = *(const v8s*)(qbase + quad * 8);
  v8s QB01 = *(const v8s*)(qbase + quad * 8 + 32);
  v8s QB10 = *(const v8s*)(qbase + 16 * 64 + quad * 8);
  v8s QB11 = *(const v8s*)(qbase + 16 * 64 + quad * 8 + 32);

  // staging: wave w fills LDS bytes [w*2048, w*2048+2048) in 2 calls of 1024B
  int j0 = sp * niter;
  const char* srcK[2]; const char* srcV[2];
  char* dstK[3][2]; char* dstV[3][2];
  #pragma unroll
  for (int k = 0; k < 2; k++){
    int row = w * 16 + k * 8 + (lane >> 3);
    int c = (lane & 7) ^ (row & 7);            // XOR swizzle on source
    srcK[k] = (const char*)gb + (size_t)j0 * 8192 + row * 128 + c * 16;
    srcV[k] = (const char*)hb + (size_t)row * 8192 + (size_t)j0 * 128 + c * 16;
    #pragma unroll
    for (int b2 = 0; b2 < 3; b2++){
      dstK[b2][k] = (char*)lK[b2] + w * 2048 + k * 1024;
      dstV[b2][k] = (char*)lV[b2] + w * 2048 + k * 1024;
    }
  }

  // loop-invariant LDS frag addresses per buffer (logical chunk ph / ph^4)
  int ph = quad ^ (l16 & 7);
  const short* kA0[3]; const short* kA1[3];
  const short* vB0[3]; const short* vB1[3];
  #pragma unroll
  for (int b2 = 0; b2 < 3; b2++){
    kA0[b2] = lK[b2] + l16 * 64 + ph * 8;
    kA1[b2] = lK[b2] + l16 * 64 + (ph ^ 4) * 8;
    vB0[b2] = lV[b2] + l16 * 64 + ph * 8;
    vB1[b2] = lV[b2] + l16 * 64 + (ph ^ 4) * 8;
  }

  v8s ones;                                   // bf16 1.0 broadcast (B-frag)
  #pragma unroll
  for (int i = 0; i < 8; i++) ones[i] = (short)0x3F80;

  v4f rz[2];                                  // rowsum acc per group
  rz[0] = (v4f){0.f, 0.f, 0.f, 0.f};
  rz[1] = (v4f){0.f, 0.f, 0.f, 0.f};
  v4f O[2][4];
  #pragma unroll
  for (int gi = 0; gi < 2; gi++)
    #pragma unroll
    for (int cb = 0; cb < 4; cb++) O[gi][cb] = (v4f){0.f, 0.f, 0.f, 0.f};

  auto stage = [&](int b2){
    #pragma unroll
    for (int k = 0; k < 2; k++){
      gload_lds16(srcK[k], dstK[b2][k]);
      gload_lds16(srcV[k], dstV[b2][k]);
      srcK[k] += 8192; srcV[k] += 128;
    }
  };

  auto compute = [&](int b2){
    // S^T(64key x 32q) = K · Q^T : st[g][cb][r] = S[q][key=cb*16+quad*4+r]
    v4f st[2][4];
    __builtin_amdgcn_s_setprio(1);
    #pragma unroll
    for (int cb = 0; cb < 4; cb++){
      v8s a0 = *(const v8s*)(kA0[b2] + cb * 1024);
      v8s a1 = *(const v8s*)(kA1[b2] + cb * 1024);
      v4f z0 = (v4f){0.f, 0.f, 0.f, 0.f};
      z0 = __builtin_amdgcn_mfma_f32_16x16x32_bf16(a0, QB00, z0, 0, 0, 0);
      st[0][cb] = __builtin_amdgcn_mfma_f32_16x16x32_bf16(a1, QB01, z0, 0, 0, 0);
      v4f z1 = (v4f){0.f, 0.f, 0.f, 0.f};
      z1 = __builtin_amdgcn_mfma_f32_16x16x32_bf16(a0, QB10, z1, 0, 0, 0);
      st[1][cb] = __builtin_amdgcn_mfma_f32_16x16x32_bf16(a1, QB11, z1, 0, 0, 0);
    }
    __builtin_amdgcn_s_setprio(0);

    // p = 2^s (raw v_exp), pack pairs via perm (bf16 trunc), b64 store to lP.
    // Half h covers original chunks 4h..4h+3 (cb = 2h, 2h+1); stored at
    // slot chunk&3 = (cb&1)*2 + (quad>>1).  Lane's 4-key run at (quad&1)*4.
    auto packhalf = [&](int gi, int h){
      #pragma unroll
      for (int cc = 0; cc < 2; cc++){
        int cb = 2 * h + cc;
        float p0 = ex2(st[gi][cb][0]);
        float p1 = ex2(st[gi][cb][1]);
        float p2 = ex2(st[gi][cb][2]);
        float p3 = ex2(st[gi][cb][3]);
        unsigned d0 = __builtin_amdgcn_perm(__float_as_uint(p1), __float_as_uint(p0), 0x07060302u);
        unsigned d1 = __builtin_amdgcn_perm(__float_as_uint(p3), __float_as_uint(p2), 0x07060302u);
        uint2 pk; pk.x = d0; pk.y = d1;
        *(uint2*)&lP[w][cc * 2 + (quad >> 1)][l16][(quad & 1) * 4] = pk;
      }
    };

    // P round trips through the 1 KiB half-buffer; same-wave DS ordering
    // guarantees each read sees its half's writes and precedes the next
    // half's overwrite.  Both reads target slot `quad`.
    packhalf(0, 0);
    v8s PA00 = *(const v8s*)&lP[w][quad][l16][0];   // chunks 0-3 of gi0
    packhalf(0, 1);
    v8s PA01 = *(const v8s*)&lP[w][quad][l16][0];   // chunks 4-7 of gi0
    packhalf(1, 0);
    v8s PA10 = *(const v8s*)&lP[w][quad][l16][0];   // chunks 0-3 of gi1
    packhalf(1, 1);
    v8s PA11 = *(const v8s*)&lP[w][quad][l16][0];   // chunks 4-7 of gi1

    // V fragments: read ONCE, reused by both q-groups (st[] is dead here,
    // so vb[] lands in freed registers; peak pressure unchanged).
    v8s vb[4][2];
    #pragma unroll
    for (int cb = 0; cb < 4; cb++){
      vb[cb][0] = *(const v8s*)(vB0[b2] + cb * 1024);
      vb[cb][1] = *(const v8s*)(vB1[b2] + cb * 1024);
    }

    __builtin_amdgcn_s_setprio(1);
    rz[0] = __builtin_amdgcn_mfma_f32_16x16x32_bf16(PA00, ones, rz[0], 0, 0, 0);
    rz[0] = __builtin_amdgcn_mfma_f32_16x16x32_bf16(PA01, ones, rz[0], 0, 0, 0);
    #pragma unroll
    for (int cb = 0; cb < 4; cb++){
      O[0][cb] = __builtin_amdgcn_mfma_f32_16x16x32_bf16(PA00, vb[cb][0], O[0][cb], 0, 0, 0);
      O[0][cb] = __builtin_amdgcn_mfma_f32_16x16x32_bf16(PA01, vb[cb][1], O[0][cb], 0, 0, 0);
    }
    rz[1] = __builtin_amdgcn_mfma_f32_16x16x32_bf16(PA10, ones, rz[1], 0, 0, 0);
    rz[1] = __builtin_amdgcn_mfma_f32_16x16x32_bf16(PA11, ones, rz[1], 0, 0, 0);
    #pragma unroll
    for (int cb = 0; cb < 4; cb++){
      O[1][cb] = __builtin_amdgcn_mfma_f32_16x16x32_bf16(PA10, vb[cb][0], O[1][cb], 0, 0, 0);
      O[1][cb] = __builtin_amdgcn_mfma_f32_16x16x32_bf16(PA11, vb[cb][1], O[1][cb], 0, 0, 0);
    }
    __builtin_amdgcn_s_setprio(0);
  };

  // One pipeline slot: drain tile t's 4 loads (keep t+2's in flight unless
  // this is the last tile), barrier, issue stage t+2, compute t.
  auto slot = [&](int tt, int b2, int bs){
    if (tt == niter - 1) asm volatile("s_waitcnt vmcnt(0)" ::: "memory");
    else                 asm volatile("s_waitcnt vmcnt(4)" ::: "memory");
    __builtin_amdgcn_sched_barrier(0);
    __builtin_amdgcn_s_barrier();
    __builtin_amdgcn_sched_barrier(0);
    if (tt + 2 < niter) stage(bs);
    compute(b2);
  };

  // 2-deep prologue: tiles 0 and 1 in flight before the first compute.
  stage(0);
  stage(1);
  int j = 0;
  for (; j + 3 <= niter; j += 3){
    slot(j,     0, 2);
    slot(j + 1, 1, 0);
    slot(j + 2, 2, 1);
  }
  if (j < niter) slot(j, 0, 2);     // niter % 3 == 1 for niter in {16, 64}

  if (direct){
    #pragma unroll
    for (int gi = 0; gi < 2; gi++){
      float inv[4];
      #pragma unroll
      for (int r = 0; r < 4; r++)
        inv[r] = 1.0f / rz[gi][r];
      #pragma unroll
      for (int cb = 0; cb < 4; cb++)
        #pragma unroll
        for (int r = 0; r < 4; r++){
          int row = q0 + m0 + gi * 16 + quad * 4 + r;
          ctx[(b * NN + row) * 64 + cb * 16 + l16] = f2bf(O[gi][cb][r] * inv[r]);
        }
    }
  } else {
    int bf = (b * 32 + qt) * 4 + sp;
    if (l16 == 0){
      #pragma unroll
      for (int gi = 0; gi < 2; gi++)
        #pragma unroll
        for (int r = 0; r < 4; r++)
          lipart[bf * 128 + m0 + gi * 16 + quad * 4 + r] = rz[gi][r];
    }
    float* Ob = Opart + (size_t)bf * 8192;
    #pragma unroll
    for (int gi = 0; gi < 2; gi++)
      #pragma unroll
      for (int cb = 0; cb < 4; cb++)
        #pragma unroll
        for (int r = 0; r < 4; r++)
          Ob[(m0 + gi * 16 + quad * 4 + r) * 64 + cb * 16 + l16] = O[gi][cb][r];
  }
}

// ---------------------------------------------------------------------------
// Kernel 3 (split path): FUSED reduce + outproj.
// out = gamma * (sum_sp Opart / li) @ Wv + bv + x.  512 blocks x 512 thr.
// Block = 64 rows x all 512 cols.  ctx never touches HBM:
//   stage A: normalize Opart/lipart in-register -> bf16 A-tile in LDS.
//   stage B: full Wvt (64 KB) with 16B-chunk XOR swizzle (conflict-free
//            B-frag reads from unpadded [512][64]).
// 8 waves: wave w -> row-group (w&3)*16, col-half w>>2 (16 col-blocks each).
// LDS = 9.2 + 64 KB = 73.2 KB -> 2 blocks/CU.
// ---------------------------------------------------------------------------
__global__ __launch_bounds__(512) void outfuse_kernel(
    const float* __restrict__ Opart,         // [256 grp][4 sp][128][64]
    const float* __restrict__ lipart,        // [256 grp][4 sp][128]
    const unsigned short* __restrict__ Wvt,  // [512][64] bf16
    const float* __restrict__ bv,
    const float* __restrict__ x,
    const float* __restrict__ gamma_p,
    float* __restrict__ out)
{
  __shared__ __align__(16) short lA[64][72];
  __shared__ __align__(16) short lB[512][64];   // XOR-swizzled 16B chunks
  int t = threadIdx.x;                   // 0..511
  int lane = t & 63;
  int w = t >> 6;
  int quad = lane >> 4, l16 = lane & 15;
  int rowbase = blockIdx.x * 64;
  float gamma = *gamma_p;

  // ---- stage A: ctx tile from split-K partials (no HBM round trip) ----
  {
    int rl = t >> 3, d8 = (t & 7) * 8;   // row-local 0..63, d offset 0..56
    int group = rowbase >> 7;            // Opart group = 128 global rows
    int inrow = (rowbase & 127) + rl;
    const float* Ob  = Opart  + (size_t)group * 32768 + inrow * 64 + d8;
    const float* lib = lipart + group * 512 + inrow;
    v4f s0 = *(const v4f*)(Ob);
    v4f s1 = *(const v4f*)(Ob + 4);
    float li = lib[0];
    #pragma unroll
    for (int sp = 1; sp < 4; sp++){
      s0 = s0 + *(const v4f*)(Ob + sp * 8192);
      s1 = s1 + *(const v4f*)(Ob + sp * 8192 + 4);
      li += lib[sp * 128];
    }
    float inv = 1.0f / li;
    v4i c = { pkbf(s0[0]*inv, s0[1]*inv), pkbf(s0[2]*inv, s0[3]*inv),
              pkbf(s1[0]*inv, s1[1]*inv), pkbf(s1[2]*inv, s1[3]*inv) };
    *(v4i*)&lA[rl][d8] = c;
  }
  // ---- stage B: Wvt with 16B-chunk XOR swizzle ----
  #pragma unroll
  for (int r = 0; r < 8; r++){
    int chunk = t + r * 512;             // 4096 = 512 rows x 8 chunks
    int row = chunk >> 3, c8 = chunk & 7;
    *(v8s*)&lB[row][(c8 ^ (row & 7)) * 8] =
        *(const v8s*)(Wvt + row * 64 + c8 * 8);
  }
  __syncthreads();

  int m0 = (w & 3) * 16;                 // row-group
  int colhalf = w >> 2;                  // 0/1 -> cols 0..255 / 256..511
  v8s A0 = *(const v8s*)&lA[m0 + l16][quad * 8];
  v8s A1 = *(const v8s*)&lA[m0 + l16][quad * 8 + 32];
  int ph = quad ^ (l16 & 7);
  v4f acc[16];
  #pragma unroll
  for (int cb = 0; cb < 16; cb++){
    int row = (colhalf * 16 + cb) * 16 + l16;
    const short* bp = &lB[row][0];
    v8s b0 = *(const v8s*)(bp + ph * 8);
    v8s b1 = *(const v8s*)(bp + (ph ^ 4) * 8);
    v4f z = (v4f){0.f, 0.f, 0.f, 0.f};
    z = __builtin_amdgcn_mfma_f32_16x16x32_bf16(A0, b0, z, 0, 0, 0);
    acc[cb] = __builtin_amdgcn_mfma_f32_16x16x32_bf16(A1, b1, z, 0, 0, 0);
  }
  #pragma unroll
  for (int cb = 0; cb < 16; cb++){
    int col = colhalf * 256 + cb * 16 + l16;
    float bvv = bv[col];
    #pragma unroll
    for (int r = 0; r < 4; r++){
      int gr = rowbase + m0 + quad * 4 + r;
      out[gr * 512 + col] = gamma * acc[cb][r] + bvv + x[gr * 512 + col];
    }
  }
}

// ---------------------------------------------------------------------------
// Kernel 3b (fallback, non-split path): out = gamma * ctx @ Wv + bv + x.
// ---------------------------------------------------------------------------
__global__ __launch_bounds__(256) void outproj_kernel(
    const unsigned short* __restrict__ ctx,
    const unsigned short* __restrict__ Wvt,  // [512][64] bf16
    const float* __restrict__ bv,
    const float* __restrict__ x,
    const float* __restrict__ gamma_p,
    float* __restrict__ out)
{
  __shared__ __align__(16) short lA[64][72];
  __shared__ __align__(16) short lB[128][72];
  int t = threadIdx.x;
  int w = t >> 6, lane = t & 63;
  int quad = lane >> 4, l16 = lane & 15;
  int rowbase = blockIdx.x * 64;
  int colbase = blockIdx.y * 128;
  float gamma = *gamma_p;

  #pragma unroll
  for (int r = 0; r < 2; r++){
    int chunk = t + r * 256;
    int row = chunk >> 3, c8 = chunk & 7;
    *(v8s*)&lA[row][c8 * 8] = *(const v8s*)(ctx + (rowbase + row) * 64 + c8 * 8);
  }
  #pragma unroll
  for (int r = 0; r < 4; r++){
    int chunk = t + r * 256;
    int row = chunk >> 3, c8 = chunk & 7;
    *(v8s*)&lB[row][c8 * 8] = *(const v8s*)(Wvt + (colbase + row) * 64 + c8 * 8);
  }
  __syncthreads();
  int m0 = w * 16;
  v8s A0 = *(const v8s*)&lA[m0 + l16][quad * 8];
  v8s A1 = *(const v8s*)&lA[m0 + l16][quad * 8 + 32];
  v4f acc[8];
  #pragma unroll
  for (int cb = 0; cb < 8; cb++){
    v8s b0 = *(const v8s*)&lB[cb * 16 + l16][quad * 8];
    v8s b1 = *(const v8s*)&lB[cb * 16 + l16][quad * 8 + 32];
    v4f z = (v4f){0.f, 0.f, 0.f, 0.f};
    z = __builtin_amdgcn_mfma_f32_16x16x32_bf16(A0, b0, z, 0, 0, 0);
    acc[cb] = __builtin_amdgcn_mfma_f32_16x16x32_bf16(A1, b1, z, 0, 0, 0);
  }
  #pragma unroll
  for (int cb = 0; cb < 8; cb++){
    int col = colbase + cb * 16 + l16;
    float bvv = bv[col];
    #pragma unroll
    for (int r = 0; r < 4; r++){
      int gr = rowbase + m0 + quad * 4 + r;
      out[gr * 512 + col] = gamma * acc[cb][r] + bvv + x[gr * 512 + col];
    }
  }
}

// ---------------------------------------------------------------------------
extern "C" void kernel_launch(void* const* d_in, const int* in_sizes, int n_in,
                              void* d_out, int out_size, void* d_ws, size_t ws_size,
                              hipStream_t stream) {
  const float* x   = (const float*)d_in[0];
  const float* Wf  = (const float*)d_in[1];
  const float* bf_ = (const float*)d_in[2];
  const float* Wg  = (const float*)d_in[3];
  const float* bg  = (const float*)d_in[4];
  const float* Wh  = (const float*)d_in[5];
  const float* bh  = (const float*)d_in[6];
  const float* Wv  = (const float*)d_in[7];
  const float* bv  = (const float*)d_in[8];
  const float* gam = (const float*)d_in[9];
  float* out = (float*)d_out;

  // workspace map (bytes):
  //   Wt   @ 0         (196608)
  //   Wvt  @ 196608    (65536)
  //   f    @ 262144    (4194304)
  //   g    @ 4456448   (4194304)
  //   ht   @ 8650752   (4194304)
  //   ctx  @ 12845056  (4194304)   (fallback path only)
  //   Opart @ 17039360 (33554432)   split-K partials [1024][128][64] f32
  //   lipart@ 50593792 (524288)     [1024][128] f32; total 51118080 (~48.8 MiB)
  char* ws = (char*)d_ws;
  unsigned short* Wt  = (unsigned short*)(ws);
  unsigned short* Wvt = (unsigned short*)(ws + 196608);
  unsigned short* f   = (unsigned short*)(ws + 262144);
  unsigned short* g   = (unsigned short*)(ws + 4456448);
  unsigned short* ht  = (unsigned short*)(ws + 8650752);
  unsigned short* ctx = (unsigned short*)(ws + 12845056);
  float* Opart  = (float*)(ws + 17039360);
  float* lipart = (float*)(ws + 50593792);

  transpose_w<<<512, 256, 0, stream>>>(Wf, Wg, Wh, Wv, Wt, Wvt);
  proj_kernel<<<512, 512, 0, stream>>>(x, Wt, bf_, bg, bh, f, g, ht);

  bool split = (ws_size >= (size_t)51118080);
  if (split){
    flash_kernel<<<dim3(32, 4, 8), 256, 0, stream>>>(f, g, ht, Opart, lipart, ctx, 16, 0);
    outfuse_kernel<<<512, 512, 0, stream>>>(Opart, lipart, Wvt, bv, x, gam, out);
  } else {
    flash_kernel<<<dim3(32, 1, 8), 256, 0, stream>>>(f, g, ht, nullptr, nullptr, ctx, 64, 1);
    outproj_kernel<<<dim3(512, 4), 256, 0, stream>>>(ctx, Wvt, bv, x, gam, out);
  }
}